// Round 6
// baseline (197.873 us; speedup 1.0000x reference)
//
#include <hip/hip_runtime.h>

#define EMBD 768
#define HS 64
#define S_LEN 4096
#define QB 32
#define BK 64
#define NSPLIT 8

typedef __attribute__((ext_vector_type(8))) short short8;
typedef __attribute__((ext_vector_type(4))) short short4_t;
typedef __attribute__((ext_vector_type(4))) float f32x4;
typedef unsigned short ushort_t;
typedef unsigned int uint_t;

static __device__ __forceinline__ ushort_t f2bf(float f) {
    union { float f; unsigned u; } x; x.f = f;
    unsigned r = x.u + 0x7fffu + ((x.u >> 16) & 1u);   // RNE
    return (ushort_t)(r >> 16);
}

static __device__ __forceinline__ uint_t cvt_pk_bf16(float lo, float hi) {
    uint_t r;
    asm volatile("v_cvt_pk_bf16_f32 %0, %1, %2" : "=v"(r) : "v"(lo), "v"(hi));
    return r;
}

static __device__ __forceinline__ short8 pack_bf8(float4 a, float4 b) {
    union { short8 s; uint_t u[4]; } r;
    r.u[0] = cvt_pk_bf16(a.x, a.y); r.u[1] = cvt_pk_bf16(a.z, a.w);
    r.u[2] = cvt_pk_bf16(b.x, b.y); r.u[3] = cvt_pk_bf16(b.z, b.w);
    return r.s;
}

static __device__ __forceinline__ void gl_lds16(const void* g, void* l) {
    __builtin_amdgcn_global_load_lds(
        (const __attribute__((address_space(1))) unsigned int*)g,
        (__attribute__((address_space(3))) unsigned int*)l, 16, 0, 0);
}

// ---------------- W prep: Wt[192][768] bf16, Wt[c][k] = W_sel[k][c%64] ----------------
__global__ __launch_bounds__(256) void wprep_kernel(
    const float* __restrict__ Wq, const float* __restrict__ Wk, const float* __restrict__ Wv,
    ushort_t* __restrict__ Wt)
{
    __shared__ float ws[64][65];
    const int blk  = blockIdx.x;           // 36 = 3 W x 12 k-blocks
    const int widx = blk / 12, kblk = blk % 12;
    const float* W = (widx == 0) ? Wq : (widx == 1) ? Wk : Wv;
    const int k0 = kblk * 64;
    const int t  = threadIdx.x;
    const int r  = t >> 2, c0 = (t & 3) * 16;
#pragma unroll
    for (int i = 0; i < 4; ++i) {
        float4 v = *(const float4*)(W + (size_t)(k0 + r) * HS + c0 + i * 4);
        ws[c0 + i*4 + 0][r] = v.x; ws[c0 + i*4 + 1][r] = v.y;
        ws[c0 + i*4 + 2][r] = v.z; ws[c0 + i*4 + 3][r] = v.w;
    }
    __syncthreads();
    const int c = t >> 2, kc = (t & 3) * 16;
    ushort_t* dst = Wt + (size_t)(widx * 64 + c) * EMBD + k0 + kc;
#pragma unroll
    for (int i = 0; i < 4; ++i) {
        short4_t p = {(short)f2bf(ws[c][kc + i*4 + 0]), (short)f2bf(ws[c][kc + i*4 + 1]),
                      (short)f2bf(ws[c][kc + i*4 + 2]), (short)f2bf(ws[c][kc + i*4 + 3])};
        *(short4_t*)(dst + i * 4) = p;
    }
}

// ---------------- QKV via MFMA: global_load_lds fp32 staging, convert on read ----------
// 512 thr = 8 waves (2 mg x 4 cg). LDS x-tile [32 rows][64 k] fp32, dbuf, source
// pre-swizzled (chunk ^= row&7) so linear LDS dest + swizzled read are conflict-light.
__global__ __launch_bounds__(512, 4) void qkv_kernel(
    const float* __restrict__ x, const ushort_t* __restrict__ Wt,
    ushort_t* __restrict__ Qg, ushort_t* __restrict__ Kg, ushort_t* __restrict__ Vtg)
{
    __shared__ float xbuf[2][32 * 64];         // 8 KB each
    __shared__ float Vs[32][65];
    const int t    = threadIdx.x;
    const int w    = t >> 6;
    const int lane = t & 63;
    const int l15  = lane & 15;
    const int l4   = lane >> 4;
    const int mg   = w >> 2;
    const int cg   = w & 3;
    const int row0 = blockIdx.x * 32;

    // staging: thread t covers LDS bytes t*16; row=t>>4, chunk=(t&15)>>1, half=t&1
    const int srow   = t >> 4;
    const int schunk = ((t & 15) >> 1) ^ (srow & 7);
    const float* gsrc = x + (size_t)(row0 + srow) * EMBD + schunk * 8 + (t & 1) * 4;
    char* ldst0 = (char*)&xbuf[0][0] + w * 1024;    // wave-uniform
    char* ldst1 = (char*)&xbuf[1][0] + w * 1024;

    const int ar = mg * 16 + l15;              // A row
    const ushort_t* wp0 = Wt + (size_t)(cg * 16 + l15) * EMBD + l4 * 8;
    const ushort_t* wp1 = wp0 + (size_t)64 * EMBD;
    const ushort_t* wp2 = wp0 + (size_t)128 * EMBD;

    f32x4 acc0 = (f32x4){0.f,0.f,0.f,0.f}, acc1 = acc0, acc2 = acc0;

    gl_lds16(gsrc, ldst0);                     // stage tile 0
    __syncthreads();                           // drains vmcnt(0)

#pragma unroll
    for (int kt = 0; kt < 12; ++kt) {
        const int cur = kt & 1;
        if (kt < 11) gl_lds16(gsrc + (kt + 1) * 64, cur ? ldst0 : ldst1);
        const char* xb = (const char*)&xbuf[cur][0];
#pragma unroll
        for (int ks = 0; ks < 2; ++ks) {
            const int ko = kt * 64 + ks * 32;
            short8 b0 = *(const short8*)(wp0 + ko);
            short8 b1 = *(const short8*)(wp1 + ko);
            short8 b2 = *(const short8*)(wp2 + ko);
            const int cofs = ((ks * 4 + l4) ^ (ar & 7)) * 32;
            float4 a0 = *(const float4*)(xb + ar * 256 + cofs);
            float4 a1 = *(const float4*)(xb + ar * 256 + cofs + 16);
            short8 af = pack_bf8(a0, a1);
            acc0 = __builtin_amdgcn_mfma_f32_16x16x32_bf16(af, b0, acc0, 0, 0, 0);
            acc1 = __builtin_amdgcn_mfma_f32_16x16x32_bf16(af, b1, acc1, 0, 0, 0);
            acc2 = __builtin_amdgcn_mfma_f32_16x16x32_bf16(af, b2, acc2, 0, 0, 0);
        }
        if (kt < 11) __syncthreads();          // vmcnt(0)+lgkm drain + barrier
    }

    // epilogue: Q (pre-scaled 1/8) / K direct, V via LDS transpose
    const size_t grow0 = (size_t)row0 + mg * 16 + l4 * 4;
    const int col = cg * 16 + l15;
#pragma unroll
    for (int r = 0; r < 4; ++r) {
        Qg[(grow0 + r) * HS + col] = f2bf(acc0[r] * 0.125f);
        Kg[(grow0 + r) * HS + col] = f2bf(acc1[r]);
        Vs[mg * 16 + l4 * 4 + r][col] = acc2[r];
    }
    __syncthreads();
    const int vcol = t >> 3, vr0 = (t & 7) * 4;
    const int bb = row0 >> 12, s0 = row0 & 4095;
    short4_t vp = {(short)f2bf(Vs[vr0][vcol]),     (short)f2bf(Vs[vr0 + 1][vcol]),
                   (short)f2bf(Vs[vr0 + 2][vcol]), (short)f2bf(Vs[vr0 + 3][vcol])};
    *(short4_t*)(Vtg + ((size_t)bb * HS + vcol) * S_LEN + s0 + vr0) = vp;
}

// ---------------- MFMA flash attention: 8-way key split, prefetched K, defer-max ------
__global__ __launch_bounds__(512, 4) void attn_kernel(
    const ushort_t* __restrict__ Qg, const ushort_t* __restrict__ Kg,
    const ushort_t* __restrict__ Vtg, float* __restrict__ out, int B)
{
    __shared__ char smem[71680];     // P: 8 x 4KB | combine accb[8][32][68]f32 + mb/lb
    const int t    = threadIdx.x;
    const int w    = t >> 6;         // 0..7 key-split
    const int lane = t & 63;
    const int l15  = lane & 15;
    const int l4   = lane >> 4;

    // XCD swizzle: batch b -> XCD pair; biggest q-tiles first
    const int g = blockIdx.x;
    int b, qt;
    if (B == 4) { b = (g & 7) >> 1; qt = (S_LEN/QB - 1) - ((g >> 3) * 2 + (g & 1)); }
    else        { b = g % B;        qt = (S_LEN/QB - 1) - (g / B); }
    const int q0 = qt * QB;
    const int ntiles = (q0 + QB + BK - 1) >> 6;

    char* myP = smem + w * 4096;     // [32 q][64 k] bf16, byte ^= ((q&7)<<4)
    const int psw = (l15 & 7) << 4;

    const ushort_t* Qbase = Qg + ((size_t)b * S_LEN + q0) * HS;
    short8 qf[2][2];
#pragma unroll
    for (int sub = 0; sub < 2; ++sub)
#pragma unroll
        for (int c = 0; c < 2; ++c)
            qf[sub][c] = *(const short8*)(Qbase + (sub * 16 + l15) * HS + c * 32 + l4 * 8);

    f32x4 acc[2][4];
#pragma unroll
    for (int i = 0; i < 2; ++i)
#pragma unroll
        for (int j = 0; j < 4; ++j) acc[i][j] = (f32x4){0.f,0.f,0.f,0.f};
    float m[2] = {-3e38f, -3e38f};
    float lsum[2] = {0.f, 0.f};

    const ushort_t* Kb_ = Kg  + (size_t)b * S_LEN * HS;
    const ushort_t* Vb_ = Vtg + (size_t)b * HS * S_LEN;

    auto process = [&](short8 (&CURB)[4][2], short8 (&NXTB)[4][2], int kb) {
        const int k0 = kb * BK;
        short8 vf[4][2];
#pragma unroll
        for (int ds = 0; ds < 4; ++ds)
#pragma unroll
            for (int ks = 0; ks < 2; ++ks)
                vf[ds][ks] = *(const short8*)(Vb_ + (size_t)(ds * 16 + l15) * S_LEN + k0 + ks * 32 + l4 * 8);
        if (kb + NSPLIT < ntiles) {
            const int kn = (kb + NSPLIT) * BK;
#pragma unroll
            for (int st = 0; st < 4; ++st)
#pragma unroll
                for (int c = 0; c < 2; ++c)
                    NXTB[st][c] = *(const short8*)(Kb_ + (size_t)(kn + st * 16 + l15) * HS + c * 32 + l4 * 8);
        }
        const bool lastTile = (kb == ntiles - 1);
#pragma unroll
        for (int sub = 0; sub < 2; ++sub) {
            f32x4 sT[4];
#pragma unroll
            for (int st = 0; st < 4; ++st) {
                f32x4 z = (f32x4){0.f,0.f,0.f,0.f};
                z = __builtin_amdgcn_mfma_f32_16x16x32_bf16(CURB[st][0], qf[sub][0], z, 0, 0, 0);
                z = __builtin_amdgcn_mfma_f32_16x16x32_bf16(CURB[st][1], qf[sub][1], z, 0, 0, 0);
                sT[st] = z;
            }
            const int q = q0 + sub * 16 + l15;
            if (lastTile) {
#pragma unroll
                for (int st = 0; st < 4; ++st)
#pragma unroll
                    for (int r = 0; r < 4; ++r)
                        if (k0 + st * 16 + l4 * 4 + r > q) sT[st][r] = -3e38f;
            }
            float a0 = fmaxf(fmaxf(sT[0][0], sT[0][1]), fmaxf(sT[0][2], sT[0][3]));
            float a1 = fmaxf(fmaxf(sT[1][0], sT[1][1]), fmaxf(sT[1][2], sT[1][3]));
            float a2 = fmaxf(fmaxf(sT[2][0], sT[2][1]), fmaxf(sT[2][2], sT[2][3]));
            float a3 = fmaxf(fmaxf(sT[3][0], sT[3][1]), fmaxf(sT[3][2], sT[3][3]));
            float mt = fmaxf(fmaxf(a0, a1), fmaxf(a2, a3));
            if (__any(mt > m[sub] + 8.f)) {           // rare: full max + rescale
                mt = fmaxf(mt, __shfl_xor(mt, 16));
                mt = fmaxf(mt, __shfl_xor(mt, 32));
                float mn = fmaxf(m[sub], mt);
                float corr = __expf(m[sub] - mn);
                lsum[sub] *= corr;
#pragma unroll
                for (int ds = 0; ds < 4; ++ds)
#pragma unroll
                    for (int r = 0; r < 4; ++r) acc[sub][ds][r] *= corr;
                m[sub] = mn;
            }
            char* pr = myP + (sub * 16 + l15) * 128;
            float la = 0.f;
#pragma unroll
            for (int st = 0; st < 4; ++st) {
                float p0 = __expf(sT[st][0] - m[sub]);
                float p1 = __expf(sT[st][1] - m[sub]);
                float p2 = __expf(sT[st][2] - m[sub]);
                float p3 = __expf(sT[st][3] - m[sub]);
                la += (p0 + p1) + (p2 + p3);
                uint2 pk; pk.x = cvt_pk_bf16(p0, p1); pk.y = cvt_pk_bf16(p2, p3);
                *(uint2*)(pr + ((st * 32 + l4 * 8) ^ psw)) = pk;
            }
            lsum[sub] += la;
            short8 pb0 = *(const short8*)(pr + ((l4 * 16) ^ psw));
            short8 pb1 = *(const short8*)(pr + ((64 + l4 * 16) ^ psw));
#pragma unroll
            for (int ds = 0; ds < 4; ++ds) {
                acc[sub][ds] = __builtin_amdgcn_mfma_f32_16x16x32_bf16(vf[ds][0], pb0, acc[sub][ds], 0, 0, 0);
                acc[sub][ds] = __builtin_amdgcn_mfma_f32_16x16x32_bf16(vf[ds][1], pb1, acc[sub][ds], 0, 0, 0);
            }
        }
    };

    short8 kfA[4][2], kfB[4][2];
    int kb = w;
    if (kb < ntiles) {
        const int k0 = kb * BK;
#pragma unroll
        for (int st = 0; st < 4; ++st)
#pragma unroll
            for (int c = 0; c < 2; ++c)
                kfA[st][c] = *(const short8*)(Kb_ + (size_t)(k0 + st * 16 + l15) * HS + c * 32 + l4 * 8);
    }
    while (kb < ntiles) {
        process(kfA, kfB, kb); kb += NSPLIT;
        if (kb >= ntiles) break;
        process(kfB, kfA, kb); kb += NSPLIT;
    }

#pragma unroll
    for (int sub = 0; sub < 2; ++sub) {
        lsum[sub] += __shfl_xor(lsum[sub], 16);
        lsum[sub] += __shfl_xor(lsum[sub], 32);
    }

    // in-block combine of 8 key-split partials
    __syncthreads();
    float* accb = (float*)smem;                        // [8][32][68]
    float* mb   = (float*)(smem + 8 * 32 * 68 * 4);    // [8][32]
    float* lb   = mb + 256;
#pragma unroll
    for (int sub = 0; sub < 2; ++sub) {
#pragma unroll
        for (int ds = 0; ds < 4; ++ds)
#pragma unroll
            for (int r = 0; r < 4; ++r)
                accb[(w * 32 + sub * 16 + l15) * 68 + ds * 16 + l4 * 4 + r] = acc[sub][ds][r];
        if (l4 == 0) {
            mb[w * 32 + sub * 16 + l15] = m[sub];
            lb[w * 32 + sub * 16 + l15] = lsum[sub];
        }
    }
    __syncthreads();

    const int row = t >> 4;                 // 0..31
    const int d0  = (t & 15) * 4;
    float mv[8], lv[8];
#pragma unroll
    for (int p = 0; p < 8; ++p) { mv[p] = mb[p * 32 + row]; lv[p] = lb[p * 32 + row]; }
    float ms = mv[0];
#pragma unroll
    for (int p = 1; p < 8; ++p) ms = fmaxf(ms, mv[p]);
    float4 o = make_float4(0.f, 0.f, 0.f, 0.f);
    float ll = 0.f;
#pragma unroll
    for (int p = 0; p < 8; ++p) {
        float e = __expf(mv[p] - ms);
        float4 a = *(const float4*)&accb[(p * 32 + row) * 68 + d0];
        o.x += a.x * e; o.y += a.y * e; o.z += a.z * e; o.w += a.w * e;
        ll += lv[p] * e;
    }
    const float inv = 1.f / ll;
    *(float4*)&out[((size_t)b * S_LEN + q0 + row) * HS + d0] =
        make_float4(o.x * inv, o.y * inv, o.z * inv, o.w * inv);
}

extern "C" void kernel_launch(void* const* d_in, const int* in_sizes, int n_in,
                              void* d_out, int out_size, void* d_ws, size_t ws_size,
                              hipStream_t stream) {
    const float* x  = (const float*)d_in[0];
    const float* Wq = (const float*)d_in[1];
    const float* Wk = (const float*)d_in[2];
    const float* Wv = (const float*)d_in[3];
    float* out = (float*)d_out;

    const int rows = in_sizes[0] / EMBD;   // B*S
    const int B    = rows / S_LEN;

    ushort_t* Qb = (ushort_t*)d_ws;
    ushort_t* Kb = Qb + (size_t)rows * HS;
    ushort_t* Vt = Kb + (size_t)rows * HS;
    ushort_t* Wt = Vt + (size_t)rows * HS;

    hipLaunchKernelGGL(wprep_kernel, dim3(36), dim3(256), 0, stream, Wq, Wk, Wv, Wt);
    hipLaunchKernelGGL(qkv_kernel, dim3(rows / 32), dim3(512), 0, stream,
                       x, Wt, Qb, Kb, Vt);
    hipLaunchKernelGGL(attn_kernel, dim3(B * (S_LEN / QB)), dim3(512), 0, stream,
                       Qb, Kb, Vt, out, B);
}

// Round 7
// 93.734 us; speedup vs baseline: 2.1110x; 2.1110x over previous
//
#include <hip/hip_runtime.h>

#define EMBD 768
#define HS 64
#define S_LEN 4096
#define QB 32
#define BK 64

typedef __attribute__((ext_vector_type(8))) short short8;
typedef __attribute__((ext_vector_type(4))) short short4_t;
typedef __attribute__((ext_vector_type(4))) float f32x4;
typedef unsigned short ushort_t;
typedef unsigned int uint_t;

static __device__ __forceinline__ ushort_t f2bf(float f) {
    union { float f; unsigned u; } x; x.f = f;
    unsigned r = x.u + 0x7fffu + ((x.u >> 16) & 1u);   // RNE
    return (ushort_t)(r >> 16);
}

static __device__ __forceinline__ uint_t cvt_pk_bf16(float lo, float hi) {
    uint_t r;
    asm volatile("v_cvt_pk_bf16_f32 %0, %1, %2" : "=v"(r) : "v"(lo), "v"(hi));
    return r;
}

static __device__ __forceinline__ short8 pack_bf8(float4 a, float4 b) {
    union { short8 s; uint_t u[4]; } r;
    r.u[0] = cvt_pk_bf16(a.x, a.y); r.u[1] = cvt_pk_bf16(a.z, a.w);
    r.u[2] = cvt_pk_bf16(b.x, b.y); r.u[3] = cvt_pk_bf16(b.z, b.w);
    return r.s;
}

static __device__ __forceinline__ void gl_lds16(const void* g, void* l) {
    __builtin_amdgcn_global_load_lds(
        (const __attribute__((address_space(1))) unsigned int*)g,
        (__attribute__((address_space(3))) unsigned int*)l, 16, 0, 0);
}

// ---------------- W prep: Wt[192][768] bf16, Wt[c][k] = W_sel[k][c%64] ----------------
__global__ __launch_bounds__(256) void wprep_kernel(
    const float* __restrict__ Wq, const float* __restrict__ Wk, const float* __restrict__ Wv,
    ushort_t* __restrict__ Wt)
{
    __shared__ float ws[64][65];
    const int blk  = blockIdx.x;           // 36 = 3 W x 12 k-blocks
    const int widx = blk / 12, kblk = blk % 12;
    const float* W = (widx == 0) ? Wq : (widx == 1) ? Wk : Wv;
    const int k0 = kblk * 64;
    const int t  = threadIdx.x;
    const int r  = t >> 2, c0 = (t & 3) * 16;
#pragma unroll
    for (int i = 0; i < 4; ++i) {
        float4 v = *(const float4*)(W + (size_t)(k0 + r) * HS + c0 + i * 4);
        ws[c0 + i*4 + 0][r] = v.x; ws[c0 + i*4 + 1][r] = v.y;
        ws[c0 + i*4 + 2][r] = v.z; ws[c0 + i*4 + 3][r] = v.w;
    }
    __syncthreads();
    const int c = t >> 2, kc = (t & 3) * 16;
    ushort_t* dst = Wt + (size_t)(widx * 64 + c) * EMBD + k0 + kc;
#pragma unroll
    for (int i = 0; i < 4; ++i) {
        short4_t p = {(short)f2bf(ws[c][kc + i*4 + 0]), (short)f2bf(ws[c][kc + i*4 + 1]),
                      (short)f2bf(ws[c][kc + i*4 + 2]), (short)f2bf(ws[c][kc + i*4 + 3])};
        *(short4_t*)(dst + i * 4) = p;
    }
}

// ---------------- QKV via MFMA: 16-row blocks (1024 blocks), gl_lds dbuf ----------------
// 256 thr = 4 waves, wave cg handles Q/K/V col-tile cg*16. LDS x-tile [16 rows][64 k]
// fp32, 16B-granule XOR swizzle (granule ^= row&7), linear dest + pre-swizzled source.
__global__ __launch_bounds__(256) void qkv_kernel(
    const float* __restrict__ x, const ushort_t* __restrict__ Wt,
    ushort_t* __restrict__ Qg, ushort_t* __restrict__ Kg, ushort_t* __restrict__ Vtg)
{
    __shared__ float xbuf[2][16 * 64];         // 4 KB each
    __shared__ float Vs[16][65];
    const int t    = threadIdx.x;
    const int cg   = t >> 6;
    const int lane = t & 63;
    const int l15  = lane & 15;
    const int l4   = lane >> 4;
    const int row0 = blockIdx.x * 16;

    // staging: thread t covers linear LDS granule16 t (byte t*16): row=t>>4, g=t&15.
    // content must be global granule g^(row&7).
    const int srow = t >> 4;
    const float* gsrc = x + (size_t)(row0 + srow) * EMBD + ((t & 15) ^ (srow & 7)) * 4;
    char* base0 = (char*)&xbuf[0][0] + cg * 1024;   // wave-uniform; lane*16 added by HW
    char* base1 = (char*)&xbuf[1][0] + cg * 1024;

    const ushort_t* wp0 = Wt + (size_t)(cg * 16 + l15) * EMBD + l4 * 8;
    const ushort_t* wp1 = wp0 + (size_t)64 * EMBD;
    const ushort_t* wp2 = wp0 + (size_t)128 * EMBD;

    f32x4 acc0 = (f32x4){0.f,0.f,0.f,0.f}, acc1 = acc0, acc2 = acc0;

    gl_lds16(gsrc, base0);
    __syncthreads();

#pragma unroll
    for (int kt = 0; kt < 12; ++kt) {
        const int cur = kt & 1;
        if (kt < 11) gl_lds16(gsrc + (kt + 1) * 64, cur ? base0 : base1);
        const char* xb = (const char*)&xbuf[cur][0];
#pragma unroll
        for (int ks = 0; ks < 2; ++ks) {
            const int ko = kt * 64 + ks * 32;
            short8 b0 = *(const short8*)(wp0 + ko);
            short8 b1 = *(const short8*)(wp1 + ko);
            short8 b2 = *(const short8*)(wp2 + ko);
            const int c32 = ks * 4 + l4;           // 32B chunk within row
            const int g0 = (2 * c32)     ^ (l15 & 7);
            const int g1 = (2 * c32 + 1) ^ (l15 & 7);
            float4 a0 = *(const float4*)(xb + l15 * 256 + g0 * 16);
            float4 a1 = *(const float4*)(xb + l15 * 256 + g1 * 16);
            short8 af = pack_bf8(a0, a1);
            acc0 = __builtin_amdgcn_mfma_f32_16x16x32_bf16(af, b0, acc0, 0, 0, 0);
            acc1 = __builtin_amdgcn_mfma_f32_16x16x32_bf16(af, b1, acc1, 0, 0, 0);
            acc2 = __builtin_amdgcn_mfma_f32_16x16x32_bf16(af, b2, acc2, 0, 0, 0);
        }
        if (kt < 11) __syncthreads();              // next tile staged; all done reading cur
    }

    // epilogue: Q (pre-scaled 1/8) / K direct, V via LDS transpose
    const size_t grow0 = (size_t)row0 + l4 * 4;
    const int col = cg * 16 + l15;
#pragma unroll
    for (int r = 0; r < 4; ++r) {
        Qg[(grow0 + r) * HS + col] = f2bf(acc0[r] * 0.125f);
        Kg[(grow0 + r) * HS + col] = f2bf(acc1[r]);
        Vs[l4 * 4 + r][col] = acc2[r];
    }
    __syncthreads();
    const int vcol = t >> 2, vr0 = (t & 3) * 4;
    const int bb = row0 >> 12, s0 = row0 & 4095;
    short4_t vp = {(short)f2bf(Vs[vr0][vcol]),     (short)f2bf(Vs[vr0 + 1][vcol]),
                   (short)f2bf(Vs[vr0 + 2][vcol]), (short)f2bf(Vs[vr0 + 3][vcol])};
    *(short4_t*)(Vtg + ((size_t)bb * HS + vcol) * S_LEN + s0 + vr0) = vp;
}

// ---------------- MFMA flash attention stage 1: 8-way key split across 2 blocks -------
// 256 thr, 4 waves; block kp in {0,1}: waves take kb = kp*4 + w, stride 8.
// Writes unnormalized partial (m, l, acc) per q-tile half.
__global__ __launch_bounds__(256) void attn_kernel(
    const ushort_t* __restrict__ Qg, const ushort_t* __restrict__ Kg,
    const ushort_t* __restrict__ Vtg,
    float* __restrict__ pacc, float* __restrict__ pm, float* __restrict__ pl, int B)
{
    __shared__ char smem[34304];     // P: 4 x 4KB | combine accb[4][32][65]f32 + mb/lb
    const int t    = threadIdx.x;
    const int w    = t >> 6;
    const int lane = t & 63;
    const int l15  = lane & 15;
    const int l4   = lane >> 4;

    const int g  = blockIdx.x;
    const int kp = g & 1;
    const int b  = (g >> 1) & 3;                       // B==4 assumed for mapping
    const int qt = (S_LEN / QB - 1) - (g >> 3);        // biggest q-tiles first
    const int q0 = qt * QB;
    const int ntiles = (q0 + QB + BK - 1) >> 6;
    const int p = (b * (S_LEN / QB) + qt) * 2 + kp;    // partial index

    char* myP = smem + w * 4096;     // [32 q][64 k] bf16, byte ^= ((q&7)<<4)
    const int psw = (l15 & 7) << 4;

    const ushort_t* Qbase = Qg + ((size_t)b * S_LEN + q0) * HS;
    short8 qf[2][2];
#pragma unroll
    for (int sub = 0; sub < 2; ++sub)
#pragma unroll
        for (int c = 0; c < 2; ++c)
            qf[sub][c] = *(const short8*)(Qbase + (sub * 16 + l15) * HS + c * 32 + l4 * 8);

    f32x4 acc[2][4];
#pragma unroll
    for (int i = 0; i < 2; ++i)
#pragma unroll
        for (int j = 0; j < 4; ++j) acc[i][j] = (f32x4){0.f,0.f,0.f,0.f};
    float m[2] = {-3e38f, -3e38f};
    float lsum[2] = {0.f, 0.f};

    const ushort_t* Kb_ = Kg  + (size_t)b * S_LEN * HS;
    const ushort_t* Vb_ = Vtg + (size_t)b * HS * S_LEN;

    auto process = [&](short8 (&CURB)[4][2], short8 (&NXTB)[4][2], int kb) {
        const int k0 = kb * BK;
        short8 vf[4][2];
#pragma unroll
        for (int ds = 0; ds < 4; ++ds)
#pragma unroll
            for (int ks = 0; ks < 2; ++ks)
                vf[ds][ks] = *(const short8*)(Vb_ + (size_t)(ds * 16 + l15) * S_LEN + k0 + ks * 32 + l4 * 8);
        if (kb + 8 < ntiles) {
            const int kn = (kb + 8) * BK;
#pragma unroll
            for (int st = 0; st < 4; ++st)
#pragma unroll
                for (int c = 0; c < 2; ++c)
                    NXTB[st][c] = *(const short8*)(Kb_ + (size_t)(kn + st * 16 + l15) * HS + c * 32 + l4 * 8);
        }
        const bool lastTile = (kb == ntiles - 1);
#pragma unroll
        for (int sub = 0; sub < 2; ++sub) {
            f32x4 sT[4];
#pragma unroll
            for (int st = 0; st < 4; ++st) {
                f32x4 z = (f32x4){0.f,0.f,0.f,0.f};
                z = __builtin_amdgcn_mfma_f32_16x16x32_bf16(CURB[st][0], qf[sub][0], z, 0, 0, 0);
                z = __builtin_amdgcn_mfma_f32_16x16x32_bf16(CURB[st][1], qf[sub][1], z, 0, 0, 0);
                sT[st] = z;
            }
            const int q = q0 + sub * 16 + l15;
            if (lastTile) {
#pragma unroll
                for (int st = 0; st < 4; ++st)
#pragma unroll
                    for (int r = 0; r < 4; ++r)
                        if (k0 + st * 16 + l4 * 4 + r > q) sT[st][r] = -3e38f;
            }
            float a0 = fmaxf(fmaxf(sT[0][0], sT[0][1]), fmaxf(sT[0][2], sT[0][3]));
            float a1 = fmaxf(fmaxf(sT[1][0], sT[1][1]), fmaxf(sT[1][2], sT[1][3]));
            float a2 = fmaxf(fmaxf(sT[2][0], sT[2][1]), fmaxf(sT[2][2], sT[2][3]));
            float a3 = fmaxf(fmaxf(sT[3][0], sT[3][1]), fmaxf(sT[3][2], sT[3][3]));
            float mt = fmaxf(fmaxf(a0, a1), fmaxf(a2, a3));
            if (__any(mt > m[sub] + 8.f)) {           // rare: full max + rescale
                mt = fmaxf(mt, __shfl_xor(mt, 16));
                mt = fmaxf(mt, __shfl_xor(mt, 32));
                float mn = fmaxf(m[sub], mt);
                float corr = __expf(m[sub] - mn);
                lsum[sub] *= corr;
#pragma unroll
                for (int ds = 0; ds < 4; ++ds)
#pragma unroll
                    for (int r = 0; r < 4; ++r) acc[sub][ds][r] *= corr;
                m[sub] = mn;
            }
            char* pr = myP + (sub * 16 + l15) * 128;
            float la = 0.f;
#pragma unroll
            for (int st = 0; st < 4; ++st) {
                float p0 = __expf(sT[st][0] - m[sub]);
                float p1 = __expf(sT[st][1] - m[sub]);
                float p2 = __expf(sT[st][2] - m[sub]);
                float p3 = __expf(sT[st][3] - m[sub]);
                la += (p0 + p1) + (p2 + p3);
                uint2 pk; pk.x = cvt_pk_bf16(p0, p1); pk.y = cvt_pk_bf16(p2, p3);
                *(uint2*)(pr + ((st * 32 + l4 * 8) ^ psw)) = pk;
            }
            lsum[sub] += la;
            short8 pb0 = *(const short8*)(pr + ((l4 * 16) ^ psw));
            short8 pb1 = *(const short8*)(pr + ((64 + l4 * 16) ^ psw));
#pragma unroll
            for (int ds = 0; ds < 4; ++ds) {
                acc[sub][ds] = __builtin_amdgcn_mfma_f32_16x16x32_bf16(vf[ds][0], pb0, acc[sub][ds], 0, 0, 0);
                acc[sub][ds] = __builtin_amdgcn_mfma_f32_16x16x32_bf16(vf[ds][1], pb1, acc[sub][ds], 0, 0, 0);
            }
        }
    };

    short8 kfA[4][2], kfB[4][2];
    int kb = kp * 4 + w;
    if (kb < ntiles) {
        const int k0 = kb * BK;
#pragma unroll
        for (int st = 0; st < 4; ++st)
#pragma unroll
            for (int c = 0; c < 2; ++c)
                kfA[st][c] = *(const short8*)(Kb_ + (size_t)(k0 + st * 16 + l15) * HS + c * 32 + l4 * 8);
    }
    while (kb < ntiles) {
        process(kfA, kfB, kb); kb += 8;
        if (kb >= ntiles) break;
        process(kfB, kfA, kb); kb += 8;
    }

#pragma unroll
    for (int sub = 0; sub < 2; ++sub) {
        lsum[sub] += __shfl_xor(lsum[sub], 16);
        lsum[sub] += __shfl_xor(lsum[sub], 32);
    }

    // in-block combine of this block's 4 wave partials
    __syncthreads();
    float* accb = (float*)smem;                       // [4][32][65]
    float* mb   = (float*)(smem + 4 * 32 * 65 * 4);   // [4][32]
    float* lb   = mb + 128;
#pragma unroll
    for (int sub = 0; sub < 2; ++sub) {
#pragma unroll
        for (int ds = 0; ds < 4; ++ds)
#pragma unroll
            for (int r = 0; r < 4; ++r)
                accb[(w * 32 + sub * 16 + l15) * 65 + ds * 16 + l4 * 4 + r] = acc[sub][ds][r];
        if (l4 == 0) {
            mb[w * 32 + sub * 16 + l15] = m[sub];
            lb[w * 32 + sub * 16 + l15] = lsum[sub];
        }
    }
    __syncthreads();

#pragma unroll
    for (int pass = 0; pass < 2; ++pass) {
        const int item = t + pass * 256;              // 512 items = 32 rows x 16 quads
        const int row  = item >> 4;
        const int d0   = (item & 15) * 4;
        float m0 = mb[row], m1 = mb[32 + row], m2 = mb[64 + row], m3 = mb[96 + row];
        float ms = fmaxf(fmaxf(m0, m1), fmaxf(m2, m3));
        float e0 = __expf(m0 - ms), e1 = __expf(m1 - ms), e2 = __expf(m2 - ms), e3 = __expf(m3 - ms);
        float4 o;
        o.x = accb[(0*32+row)*65 + d0    ] * e0 + accb[(1*32+row)*65 + d0    ] * e1
            + accb[(2*32+row)*65 + d0    ] * e2 + accb[(3*32+row)*65 + d0    ] * e3;
        o.y = accb[(0*32+row)*65 + d0 + 1] * e0 + accb[(1*32+row)*65 + d0 + 1] * e1
            + accb[(2*32+row)*65 + d0 + 1] * e2 + accb[(3*32+row)*65 + d0 + 1] * e3;
        o.z = accb[(0*32+row)*65 + d0 + 2] * e0 + accb[(1*32+row)*65 + d0 + 2] * e1
            + accb[(2*32+row)*65 + d0 + 2] * e2 + accb[(3*32+row)*65 + d0 + 2] * e3;
        o.w = accb[(0*32+row)*65 + d0 + 3] * e0 + accb[(1*32+row)*65 + d0 + 3] * e1
            + accb[(2*32+row)*65 + d0 + 3] * e2 + accb[(3*32+row)*65 + d0 + 3] * e3;
        *(float4*)&pacc[((size_t)p * 32 + row) * 64 + d0] = o;
        if (d0 == 0) {
            float ll = lb[row] * e0 + lb[32 + row] * e1 + lb[64 + row] * e2 + lb[96 + row] * e3;
            pm[p * 32 + row] = ms;
            pl[p * 32 + row] = ll;
        }
    }
}

// ---------------- Stage 2: combine the 2 cross-block partials per q-tile ----------------
__global__ __launch_bounds__(512) void combine_kernel(
    const float* __restrict__ pacc, const float* __restrict__ pm, const float* __restrict__ pl,
    float* __restrict__ out)
{
    const int g  = blockIdx.x;          // (b*128 + qt)
    const int t  = threadIdx.x;
    const int row = t >> 4;             // 0..31
    const int d0  = (t & 15) * 4;
    const int p0 = g * 2, p1 = p0 + 1;
    float m0 = pm[p0 * 32 + row], m1 = pm[p1 * 32 + row];
    float l0 = pl[p0 * 32 + row], l1 = pl[p1 * 32 + row];
    float ms = fmaxf(m0, m1);
    float e0 = __expf(m0 - ms), e1 = __expf(m1 - ms);
    float4 a0 = *(const float4*)&pacc[((size_t)p0 * 32 + row) * 64 + d0];
    float4 a1 = *(const float4*)&pacc[((size_t)p1 * 32 + row) * 64 + d0];
    float inv = 1.f / (l0 * e0 + l1 * e1);
    float4 o = make_float4((a0.x * e0 + a1.x * e1) * inv, (a0.y * e0 + a1.y * e1) * inv,
                           (a0.z * e0 + a1.z * e1) * inv, (a0.w * e0 + a1.w * e1) * inv);
    *(float4*)&out[((size_t)g * 32 + row) * 64 + d0] = o;
}

extern "C" void kernel_launch(void* const* d_in, const int* in_sizes, int n_in,
                              void* d_out, int out_size, void* d_ws, size_t ws_size,
                              hipStream_t stream) {
    const float* x  = (const float*)d_in[0];
    const float* Wq = (const float*)d_in[1];
    const float* Wk = (const float*)d_in[2];
    const float* Wv = (const float*)d_in[3];
    float* out = (float*)d_out;

    const int rows = in_sizes[0] / EMBD;   // B*S = 16384
    const int B    = rows / S_LEN;         // 4
    const int nqt  = S_LEN / QB;           // 128

    ushort_t* Qb = (ushort_t*)d_ws;
    ushort_t* Kb = Qb + (size_t)rows * HS;
    ushort_t* Vt = Kb + (size_t)rows * HS;
    ushort_t* Wt = Vt + (size_t)rows * HS;
    float* pacc = (float*)(Wt + 192 * EMBD);
    float* pm   = pacc + (size_t)B * nqt * 2 * 32 * 64;
    float* pl   = pm + (size_t)B * nqt * 2 * 32;

    hipLaunchKernelGGL(wprep_kernel, dim3(36), dim3(256), 0, stream, Wq, Wk, Wv, Wt);
    hipLaunchKernelGGL(qkv_kernel, dim3(rows / 16), dim3(256), 0, stream,
                       x, Wt, Qb, Kb, Vt);
    hipLaunchKernelGGL(attn_kernel, dim3(B * nqt * 2), dim3(256), 0, stream,
                       Qb, Kb, Vt, pacc, pm, pl, B);
    hipLaunchKernelGGL(combine_kernel, dim3(B * nqt), dim3(512), 0, stream,
                       pacc, pm, pl, out);
}

// Round 8
// 80.451 us; speedup vs baseline: 2.4595x; 1.1651x over previous
//
#include <hip/hip_runtime.h>

#define EMBD 768
#define HS 64
#define S_LEN 4096
#define BK 64

typedef __attribute__((ext_vector_type(8))) short short8;
typedef __attribute__((ext_vector_type(4))) short short4_t;
typedef __attribute__((ext_vector_type(4))) float f32x4;
typedef unsigned short ushort_t;
typedef unsigned int uint_t;

static __device__ __forceinline__ ushort_t f2bf(float f) {
    union { float f; unsigned u; } x; x.f = f;
    unsigned r = x.u + 0x7fffu + ((x.u >> 16) & 1u);   // RNE
    return (ushort_t)(r >> 16);
}

static __device__ __forceinline__ uint_t cvt_pk_bf16(float lo, float hi) {
    uint_t r;
    asm volatile("v_cvt_pk_bf16_f32 %0, %1, %2" : "=v"(r) : "v"(lo), "v"(hi));
    return r;
}

static __device__ __forceinline__ short8 pack_bf8(float4 a, float4 b) {
    union { short8 s; uint_t u[4]; } r;
    r.u[0] = cvt_pk_bf16(a.x, a.y); r.u[1] = cvt_pk_bf16(a.z, a.w);
    r.u[2] = cvt_pk_bf16(b.x, b.y); r.u[3] = cvt_pk_bf16(b.z, b.w);
    return r.s;
}

static __device__ __forceinline__ void gl_lds16(const void* g, void* l) {
    __builtin_amdgcn_global_load_lds(
        (const __attribute__((address_space(1))) unsigned int*)g,
        (__attribute__((address_space(3))) unsigned int*)l, 16, 0, 0);
}

// ---------------- W prep: Wt[192][768] bf16, Wt[c][k] = W_sel[k][c%64] ----------------
__global__ __launch_bounds__(256) void wprep_kernel(
    const float* __restrict__ Wq, const float* __restrict__ Wk, const float* __restrict__ Wv,
    ushort_t* __restrict__ Wt)
{
    __shared__ float ws[64][65];
    const int blk  = blockIdx.x;           // 36 = 3 W x 12 k-blocks
    const int widx = blk / 12, kblk = blk % 12;
    const float* W = (widx == 0) ? Wq : (widx == 1) ? Wk : Wv;
    const int k0 = kblk * 64;
    const int t  = threadIdx.x;
    const int r  = t >> 2, c0 = (t & 3) * 16;
#pragma unroll
    for (int i = 0; i < 4; ++i) {
        float4 v = *(const float4*)(W + (size_t)(k0 + r) * HS + c0 + i * 4);
        ws[c0 + i*4 + 0][r] = v.x; ws[c0 + i*4 + 1][r] = v.y;
        ws[c0 + i*4 + 2][r] = v.z; ws[c0 + i*4 + 3][r] = v.w;
    }
    __syncthreads();
    const int c = t >> 2, kc = (t & 3) * 16;
    ushort_t* dst = Wt + (size_t)(widx * 64 + c) * EMBD + k0 + kc;
#pragma unroll
    for (int i = 0; i < 4; ++i) {
        short4_t p = {(short)f2bf(ws[c][kc + i*4 + 0]), (short)f2bf(ws[c][kc + i*4 + 1]),
                      (short)f2bf(ws[c][kc + i*4 + 2]), (short)f2bf(ws[c][kc + i*4 + 3])};
        *(short4_t*)(dst + i * 4) = p;
    }
}

// ---------------- QKV via MFMA: gl_lds dbuf + Wt register ping-pong prefetch ----------
__global__ __launch_bounds__(256) void qkv_kernel(
    const float* __restrict__ x, const ushort_t* __restrict__ Wt,
    ushort_t* __restrict__ Qg, ushort_t* __restrict__ Kg, ushort_t* __restrict__ Vtg)
{
    __shared__ float xbuf[2][16 * 64];         // 4 KB each
    __shared__ float Vs[16][65];
    const int t    = threadIdx.x;
    const int cg   = t >> 6;
    const int lane = t & 63;
    const int l15  = lane & 15;
    const int l4   = lane >> 4;
    const int row0 = blockIdx.x * 16;

    const int srow = t >> 4;
    const float* gsrc = x + (size_t)(row0 + srow) * EMBD + ((t & 15) ^ (srow & 7)) * 4;
    char* base0 = (char*)&xbuf[0][0] + cg * 1024;   // wave-uniform; lane*16 added by HW
    char* base1 = (char*)&xbuf[1][0] + cg * 1024;

    const ushort_t* wp0 = Wt + (size_t)(cg * 16 + l15) * EMBD + l4 * 8;
    const ushort_t* wp1 = wp0 + (size_t)64 * EMBD;
    const ushort_t* wp2 = wp0 + (size_t)128 * EMBD;

    f32x4 acc0 = (f32x4){0.f,0.f,0.f,0.f}, acc1 = acc0, acc2 = acc0;
    short8 wb[2][3][2];

    // prologue: stage x tile 0; preload W frags for kt 0 and 1
    gl_lds16(gsrc, base0);
#pragma unroll
    for (int ks = 0; ks < 2; ++ks) {
        wb[0][0][ks] = *(const short8*)(wp0 + ks * 32);
        wb[0][1][ks] = *(const short8*)(wp1 + ks * 32);
        wb[0][2][ks] = *(const short8*)(wp2 + ks * 32);
        wb[1][0][ks] = *(const short8*)(wp0 + 64 + ks * 32);
        wb[1][1][ks] = *(const short8*)(wp1 + 64 + ks * 32);
        wb[1][2][ks] = *(const short8*)(wp2 + 64 + ks * 32);
    }
    __syncthreads();

#pragma unroll
    for (int kt = 0; kt < 12; ++kt) {
        const int cur = kt & 1;
        if (kt < 11) gl_lds16(gsrc + (kt + 1) * 64, cur ? base0 : base1);
        const char* xb = (const char*)&xbuf[cur][0];
#pragma unroll
        for (int ks = 0; ks < 2; ++ks) {
            short8 b0 = wb[cur][0][ks], b1 = wb[cur][1][ks], b2 = wb[cur][2][ks];
            const int c32 = ks * 4 + l4;
            const int g0 = (2 * c32)     ^ (l15 & 7);
            const int g1 = (2 * c32 + 1) ^ (l15 & 7);
            float4 a0 = *(const float4*)(xb + l15 * 256 + g0 * 16);
            float4 a1 = *(const float4*)(xb + l15 * 256 + g1 * 16);
            short8 af = pack_bf8(a0, a1);
            acc0 = __builtin_amdgcn_mfma_f32_16x16x32_bf16(af, b0, acc0, 0, 0, 0);
            acc1 = __builtin_amdgcn_mfma_f32_16x16x32_bf16(af, b1, acc1, 0, 0, 0);
            acc2 = __builtin_amdgcn_mfma_f32_16x16x32_bf16(af, b2, acc2, 0, 0, 0);
        }
        if (kt < 10) {                         // prefetch W frags for kt+2
            const int ko = (kt + 2) * 64;
#pragma unroll
            for (int ks = 0; ks < 2; ++ks) {
                wb[cur][0][ks] = *(const short8*)(wp0 + ko + ks * 32);
                wb[cur][1][ks] = *(const short8*)(wp1 + ko + ks * 32);
                wb[cur][2][ks] = *(const short8*)(wp2 + ko + ks * 32);
            }
        }
        if (kt < 11) __syncthreads();
    }

    // epilogue: Q (pre-scaled 1/8) / K direct, V via LDS transpose
    const size_t grow0 = (size_t)row0 + l4 * 4;
    const int col = cg * 16 + l15;
#pragma unroll
    for (int r = 0; r < 4; ++r) {
        Qg[(grow0 + r) * HS + col] = f2bf(acc0[r] * 0.125f);
        Kg[(grow0 + r) * HS + col] = f2bf(acc1[r]);
        Vs[l4 * 4 + r][col] = acc2[r];
    }
    __syncthreads();
    const int vcol = t >> 2, vr0 = (t & 3) * 4;
    const int bb = row0 >> 12, s0 = row0 & 4095;
    short4_t vp = {(short)f2bf(Vs[vr0][vcol]),     (short)f2bf(Vs[vr0 + 1][vcol]),
                   (short)f2bf(Vs[vr0 + 2][vcol]), (short)f2bf(Vs[vr0 + 3][vcol])};
    *(short4_t*)(Vtg + ((size_t)bb * HS + vcol) * S_LEN + s0 + vr0) = vp;
}

// ---------------- Flash attention: 64-q-row blocks, shared LDS K/V staging -------------
// 256 uniform blocks: (batch b, pair jp, parity v). Block runs ranges jp and 63-jp
// sequentially; processes key-tiles t ≡ v (mod 2). 4 waves = 4 q-subs share each tile.
__global__ __launch_bounds__(256) void attn_kernel(
    const ushort_t* __restrict__ Qg, const ushort_t* __restrict__ Kg,
    const ushort_t* __restrict__ Vtg,
    float* __restrict__ pacc, float* __restrict__ pm, float* __restrict__ pl)
{
    __shared__ char smem[40960];   // K dbuf 16K | V dbuf 16K | P 4x2K
    const int t    = threadIdx.x;
    const int w    = t >> 6;
    const int lane = t & 63;
    const int l15  = lane & 15;
    const int l4   = lane >> 4;

    const int g    = blockIdx.x;
    const int b    = (g & 7) >> 1;                 // batch -> XCD pair (pinning)
    const int rest = g >> 3;
    const int jp   = ((rest & 15) << 1) | (g & 1); // pair index 0..31
    const int v    = rest >> 4;                    // key parity 0/1

    const ushort_t* Kb_ = Kg  + (size_t)b * S_LEN * HS;
    const ushort_t* Vb_ = Vtg + (size_t)b * HS * S_LEN;
    const ushort_t* Qb_ = Qg  + (size_t)b * S_LEN * HS;

    char* myP = smem + 32768 + w * 2048;           // P[16 q][64 k] bf16
    const int psw = (l15 & 7) << 4;

    auto stage = [&](int k0, int db) {
#pragma unroll
        for (int i = 0; i < 2; ++i) {
            const int row = w * 16 + i * 8 + (lane >> 3);
            const int c   = lane & 7;
            gl_lds16(Kb_ + (size_t)(k0 + row) * HS + ((c ^ (row & 7)) * 8),
                     smem + db * 8192 + w * 2048 + i * 1024);
            gl_lds16(Vb_ + (size_t)row * S_LEN + k0 + ((c ^ (row & 7)) * 8),
                     smem + 16384 + db * 8192 + w * 2048 + i * 1024);
        }
    };

    auto run_phase = [&](int r, int pidx) {
        const int q0r = r * BK;
        const int nt  = r + 1;
        const int q   = q0r + w * 16 + l15;
        const ushort_t* qrow = Qb_ + (size_t)q * HS;
        short8 qf0 = *(const short8*)(qrow + l4 * 8);
        short8 qf1 = *(const short8*)(qrow + 32 + l4 * 8);
        f32x4 acc[4];
#pragma unroll
        for (int j = 0; j < 4; ++j) acc[j] = (f32x4){0.f,0.f,0.f,0.f};
        float mm = -3e38f, ls = 0.f;

        __syncthreads();                           // prior-phase readers done
        if (v < nt) stage(v * BK, 0);
        int db = 0;
        for (int tt = v; tt < nt; tt += 2, db ^= 1) {
            __syncthreads();                       // staged(tt) complete (vmcnt drain)
            if (tt + 2 < nt) stage((tt + 2) * BK, db ^ 1);
            const char* Kt  = smem + db * 8192;
            const char* Vt2 = smem + 16384 + db * 8192;

            f32x4 sT[4];
#pragma unroll
            for (int st = 0; st < 4; ++st) {
                const int krow = st * 16 + l15;
                const char* krb = Kt + krow * 128;
                const int sw = krow & 7;
                short8 kc0 = *(const short8*)(krb + ((l4 ^ sw) << 4));
                short8 kc1 = *(const short8*)(krb + (((4 + l4) ^ sw) << 4));
                f32x4 z = (f32x4){0.f,0.f,0.f,0.f};
                z = __builtin_amdgcn_mfma_f32_16x16x32_bf16(kc0, qf0, z, 0, 0, 0);
                z = __builtin_amdgcn_mfma_f32_16x16x32_bf16(kc1, qf1, z, 0, 0, 0);
                sT[st] = z;
            }
            if (tt == r) {                         // diagonal tile: causal mask
#pragma unroll
                for (int st = 0; st < 4; ++st)
#pragma unroll
                    for (int rr = 0; rr < 4; ++rr)
                        if (tt * BK + st * 16 + l4 * 4 + rr > q) sT[st][rr] = -3e38f;
            }
            float a0 = fmaxf(fmaxf(sT[0][0], sT[0][1]), fmaxf(sT[0][2], sT[0][3]));
            float a1 = fmaxf(fmaxf(sT[1][0], sT[1][1]), fmaxf(sT[1][2], sT[1][3]));
            float a2 = fmaxf(fmaxf(sT[2][0], sT[2][1]), fmaxf(sT[2][2], sT[2][3]));
            float a3 = fmaxf(fmaxf(sT[3][0], sT[3][1]), fmaxf(sT[3][2], sT[3][3]));
            float mt = fmaxf(fmaxf(a0, a1), fmaxf(a2, a3));
            if (__any(mt > mm + 8.f)) {            // rare: full max + rescale
                mt = fmaxf(mt, __shfl_xor(mt, 16));
                mt = fmaxf(mt, __shfl_xor(mt, 32));
                float mn = fmaxf(mm, mt);
                float corr = __expf(mm - mn);
                ls *= corr;
#pragma unroll
                for (int ds = 0; ds < 4; ++ds)
#pragma unroll
                    for (int rr = 0; rr < 4; ++rr) acc[ds][rr] *= corr;
                mm = mn;
            }
            char* pr = myP + l15 * 128;
            float la = 0.f;
#pragma unroll
            for (int st = 0; st < 4; ++st) {
                float p0 = __expf(sT[st][0] - mm);
                float p1 = __expf(sT[st][1] - mm);
                float p2 = __expf(sT[st][2] - mm);
                float p3 = __expf(sT[st][3] - mm);
                la += (p0 + p1) + (p2 + p3);
                uint2 pk; pk.x = cvt_pk_bf16(p0, p1); pk.y = cvt_pk_bf16(p2, p3);
                *(uint2*)(pr + ((st * 32 + l4 * 8) ^ psw)) = pk;
            }
            ls += la;
            short8 pb0 = *(const short8*)(pr + ((l4 * 16) ^ psw));
            short8 pb1 = *(const short8*)(pr + ((64 + l4 * 16) ^ psw));
#pragma unroll
            for (int ds = 0; ds < 4; ++ds) {
                const int vrow = ds * 16 + l15;
                const char* vrb = Vt2 + vrow * 128;
                const int sw2 = vrow & 7;
                short8 v0 = *(const short8*)(vrb + ((l4 ^ sw2) << 4));
                short8 v1 = *(const short8*)(vrb + (((4 + l4) ^ sw2) << 4));
                acc[ds] = __builtin_amdgcn_mfma_f32_16x16x32_bf16(v0, pb0, acc[ds], 0, 0, 0);
                acc[ds] = __builtin_amdgcn_mfma_f32_16x16x32_bf16(v1, pb1, acc[ds], 0, 0, 0);
            }
        }

        ls += __shfl_xor(ls, 16);
        ls += __shfl_xor(ls, 32);
        float* pa = pacc + ((size_t)pidx * 64 + w * 16 + l15) * 64 + l4 * 4;
#pragma unroll
        for (int ds = 0; ds < 4; ++ds) *(f32x4*)(pa + ds * 16) = acc[ds];
        if (l4 == 0) {
            pm[pidx * 64 + w * 16 + l15] = mm;
            pl[pidx * 64 + w * 16 + l15] = ls;
        }
    };

    run_phase(jp,      (b * 64 + jp) * 2 + v);
    run_phase(63 - jp, (b * 64 + 63 - jp) * 2 + v);
}

// ---------------- Stage 2: combine the 2 parity partials per 64-row range -------------
__global__ __launch_bounds__(256) void combine_kernel(
    const float* __restrict__ pacc, const float* __restrict__ pm, const float* __restrict__ pl,
    float* __restrict__ out)
{
    const int g   = blockIdx.x;        // b*64 + r
    const int t   = threadIdx.x;
    const int row = t >> 2;            // 0..63
    const int d0  = (t & 3) * 16;
    const int p0  = g * 2, p1 = p0 + 1;
    float m0 = pm[p0 * 64 + row], m1 = pm[p1 * 64 + row];
    float l0 = pl[p0 * 64 + row], l1 = pl[p1 * 64 + row];
    float ms = fmaxf(m0, m1);
    float e0 = __expf(m0 - ms), e1 = __expf(m1 - ms);
    float inv = 1.f / (l0 * e0 + l1 * e1);
    const float4* a0p = (const float4*)&pacc[((size_t)p0 * 64 + row) * 64 + d0];
    const float4* a1p = (const float4*)&pacc[((size_t)p1 * 64 + row) * 64 + d0];
    float4* op = (float4*)&out[((size_t)g * 64 + row) * 64 + d0];
#pragma unroll
    for (int i = 0; i < 4; ++i) {
        float4 a0 = a0p[i], a1 = a1p[i];
        op[i] = make_float4((a0.x * e0 + a1.x * e1) * inv, (a0.y * e0 + a1.y * e1) * inv,
                            (a0.z * e0 + a1.z * e1) * inv, (a0.w * e0 + a1.w * e1) * inv);
    }
}

extern "C" void kernel_launch(void* const* d_in, const int* in_sizes, int n_in,
                              void* d_out, int out_size, void* d_ws, size_t ws_size,
                              hipStream_t stream) {
    const float* x  = (const float*)d_in[0];
    const float* Wq = (const float*)d_in[1];
    const float* Wk = (const float*)d_in[2];
    const float* Wv = (const float*)d_in[3];
    float* out = (float*)d_out;

    const int rows = in_sizes[0] / EMBD;   // B*S = 16384
    const int B    = rows / S_LEN;         // 4

    ushort_t* Qb = (ushort_t*)d_ws;
    ushort_t* Kb = Qb + (size_t)rows * HS;
    ushort_t* Vt = Kb + (size_t)rows * HS;
    ushort_t* Wt = Vt + (size_t)rows * HS;
    float* pacc = (float*)(Wt + 192 * EMBD);                 // [B*64*2][64][64] f32 = 8MB
    float* pm   = pacc + (size_t)B * 64 * 2 * 64 * 64;
    float* pl   = pm + (size_t)B * 64 * 2 * 64;

    hipLaunchKernelGGL(wprep_kernel, dim3(36), dim3(256), 0, stream, Wq, Wk, Wv, Wt);
    hipLaunchKernelGGL(qkv_kernel, dim3(rows / 16), dim3(256), 0, stream,
                       x, Wt, Qb, Kb, Vt);
    hipLaunchKernelGGL(attn_kernel, dim3(B * 64), dim3(256), 0, stream,
                       Qb, Kb, Vt, pacc, pm, pl);
    hipLaunchKernelGGL(combine_kernel, dim3(B * 64), dim3(256), 0, stream,
                       pacc, pm, pl, out);
}

// Round 9
// 75.703 us; speedup vs baseline: 2.6138x; 1.0627x over previous
//
#include <hip/hip_runtime.h>

#define EMBD 768
#define HS 64
#define S_LEN 4096
#define BK 64

typedef __attribute__((ext_vector_type(8))) short short8;
typedef __attribute__((ext_vector_type(4))) short short4_t;
typedef __attribute__((ext_vector_type(4))) float f32x4;
typedef unsigned short ushort_t;
typedef unsigned int uint_t;

static __device__ __forceinline__ ushort_t f2bf(float f) {
    union { float f; unsigned u; } x; x.f = f;
    unsigned r = x.u + 0x7fffu + ((x.u >> 16) & 1u);   // RNE
    return (ushort_t)(r >> 16);
}

static __device__ __forceinline__ uint_t cvt_pk_bf16(float lo, float hi) {
    uint_t r;
    asm volatile("v_cvt_pk_bf16_f32 %0, %1, %2" : "=v"(r) : "v"(lo), "v"(hi));
    return r;
}

static __device__ __forceinline__ short4_t cvt4(float4 v) {
    union { short4_t s; uint_t u[2]; } r;
    r.u[0] = cvt_pk_bf16(v.x, v.y);
    r.u[1] = cvt_pk_bf16(v.z, v.w);
    return r.s;
}

static __device__ __forceinline__ void gl_lds16(const void* g, void* l) {
    __builtin_amdgcn_global_load_lds(
        (const __attribute__((address_space(1))) unsigned int*)g,
        (__attribute__((address_space(3))) unsigned int*)l, 16, 0, 0);
}

// ---------------- W prep: Wt[192][768] bf16, Wt[c][k] = W_sel[k][c%64] ----------------
__global__ __launch_bounds__(256) void wprep_kernel(
    const float* __restrict__ Wq, const float* __restrict__ Wk, const float* __restrict__ Wv,
    ushort_t* __restrict__ Wt)
{
    __shared__ float ws[64][65];
    const int blk  = blockIdx.x;           // 36 = 3 W x 12 k-blocks
    const int widx = blk / 12, kblk = blk % 12;
    const float* W = (widx == 0) ? Wq : (widx == 1) ? Wk : Wv;
    const int k0 = kblk * 64;
    const int t  = threadIdx.x;
    const int r  = t >> 2, c0 = (t & 3) * 16;
#pragma unroll
    for (int i = 0; i < 4; ++i) {
        float4 v = *(const float4*)(W + (size_t)(k0 + r) * HS + c0 + i * 4);
        ws[c0 + i*4 + 0][r] = v.x; ws[c0 + i*4 + 1][r] = v.y;
        ws[c0 + i*4 + 2][r] = v.z; ws[c0 + i*4 + 3][r] = v.w;
    }
    __syncthreads();
    const int c = t >> 2, kc = (t & 3) * 16;
    ushort_t* dst = Wt + (size_t)(widx * 64 + c) * EMBD + k0 + kc;
#pragma unroll
    for (int i = 0; i < 4; ++i) {
        short4_t p = {(short)f2bf(ws[c][kc + i*4 + 0]), (short)f2bf(ws[c][kc + i*4 + 1]),
                      (short)f2bf(ws[c][kc + i*4 + 2]), (short)f2bf(ws[c][kc + i*4 + 3])};
        *(short4_t*)(dst + i * 4) = p;
    }
}

// ---------------- QKV via MFMA: depth-3 reg pipeline, raw barrier (no vmcnt drain) ----
// 512 thr = 8 waves (2 mg x 4 cg). LDS bf16 x-tile [32 rows][64 k], dbuf, XOR-swizzled
// 16B granules. Per thread: 1 float4 stage-load/tile, 3 tiles in flight.
__global__ __launch_bounds__(512) void qkv_kernel(
    const float* __restrict__ x, const ushort_t* __restrict__ Wt,
    ushort_t* __restrict__ Qg, ushort_t* __restrict__ Kg, ushort_t* __restrict__ Vtg)
{
    __shared__ ushort_t xsb[2][32 * 64];       // 4 KB each
    __shared__ float Vs[32][65];
    const int t    = threadIdx.x;
    const int w    = t >> 6;
    const int lane = t & 63;
    const int l15  = lane & 15;
    const int l4   = lane >> 4;
    const int mg   = w >> 2;
    const int cg   = w & 3;
    const int row0 = blockIdx.x * 32;

    // stage map: thread t covers row srow = t>>4, floats sq*4..sq*4+3 of the 64-k tile
    const int srow = t >> 4, sq = t & 15;
    const float4* xsrc = (const float4*)(x + (size_t)(row0 + srow) * EMBD) + sq;
    const int wofs = srow * 128 + (((sq >> 1) ^ (srow & 7)) << 4) + (sq & 1) * 8;

    const ushort_t* wp0 = Wt + (size_t)(cg * 16 + l15) * EMBD + l4 * 8;
    const ushort_t* wp1 = wp0 + (size_t)64 * EMBD;
    const ushort_t* wp2 = wp0 + (size_t)128 * EMBD;

    const int ar = mg * 16 + l15;              // A row
    const char* arow0 = (const char*)xsb[0] + ar * 128;
    const char* arow1 = (const char*)xsb[1] + ar * 128;
    const int as0 = ((0 + l4) ^ (ar & 7)) << 4;    // ks=0 granule byte
    const int as1 = ((4 + l4) ^ (ar & 7)) << 4;    // ks=1 granule byte

    f32x4 acc0 = (f32x4){0.f,0.f,0.f,0.f}, acc1 = acc0, acc2 = acc0;

    float4 xr[3];                              // tiles kt+1..kt+3 (const-indexed)
    {
        float4 x0 = xsrc[0];
        xr[0] = xsrc[16];
        xr[1] = xsrc[32];
        xr[2] = xsrc[48];
        *(short4_t*)((char*)xsb[0] + wofs) = cvt4(x0);
    }
    asm volatile("s_waitcnt lgkmcnt(0)" ::: "memory");
    __builtin_amdgcn_s_barrier();

#pragma unroll
    for (int kt = 0; kt < 12; ++kt) {
        const char* arb = (kt & 1) ? arow1 : arow0;
        if (kt < 11)                           // write tile kt+1 into the other buffer
            *(short4_t*)((char*)xsb[(kt & 1) ^ 1] + wofs) = cvt4(xr[kt % 3]);
        // W fragments for kt (issued before the x refill: older in vmcnt FIFO)
        const int ko = kt * 64;
        short8 b00 = *(const short8*)(wp0 + ko);
        short8 b01 = *(const short8*)(wp1 + ko);
        short8 b02 = *(const short8*)(wp2 + ko);
        short8 b10 = *(const short8*)(wp0 + ko + 32);
        short8 b11 = *(const short8*)(wp1 + ko + 32);
        short8 b12 = *(const short8*)(wp2 + ko + 32);
        if (kt < 8) xr[kt % 3] = xsrc[(kt + 4) * 16];   // refill slot with tile kt+4
        short8 af0 = *(const short8*)(arb + as0);
        short8 af1 = *(const short8*)(arb + as1);
        acc0 = __builtin_amdgcn_mfma_f32_16x16x32_bf16(af0, b00, acc0, 0, 0, 0);
        acc1 = __builtin_amdgcn_mfma_f32_16x16x32_bf16(af0, b01, acc1, 0, 0, 0);
        acc2 = __builtin_amdgcn_mfma_f32_16x16x32_bf16(af0, b02, acc2, 0, 0, 0);
        acc0 = __builtin_amdgcn_mfma_f32_16x16x32_bf16(af1, b10, acc0, 0, 0, 0);
        acc1 = __builtin_amdgcn_mfma_f32_16x16x32_bf16(af1, b11, acc1, 0, 0, 0);
        acc2 = __builtin_amdgcn_mfma_f32_16x16x32_bf16(af1, b12, acc2, 0, 0, 0);
        if (kt < 11) {
            asm volatile("s_waitcnt lgkmcnt(0)" ::: "memory");   // ds_write landed
            __builtin_amdgcn_s_barrier();                        // NO vmcnt drain
        }
    }

    // epilogue: Q (pre-scaled 1/8) / K direct, V via LDS transpose
    const size_t grow0 = (size_t)row0 + mg * 16 + l4 * 4;
    const int col = cg * 16 + l15;
#pragma unroll
    for (int r = 0; r < 4; ++r) {
        Qg[(grow0 + r) * HS + col] = f2bf(acc0[r] * 0.125f);
        Kg[(grow0 + r) * HS + col] = f2bf(acc1[r]);
        Vs[mg * 16 + l4 * 4 + r][col] = acc2[r];
    }
    __syncthreads();
    const int vcol = t >> 3, vr0 = (t & 7) * 4;
    const int bb = row0 >> 12, s0 = row0 & 4095;
    short4_t vp = {(short)f2bf(Vs[vr0][vcol]),     (short)f2bf(Vs[vr0 + 1][vcol]),
                   (short)f2bf(Vs[vr0 + 2][vcol]), (short)f2bf(Vs[vr0 + 3][vcol])};
    *(short4_t*)(Vtg + ((size_t)bb * HS + vcol) * S_LEN + s0 + vr0) = vp;
}

// ---------------- Flash attention: 64-q-row blocks, 4-way key parity ------------------
// 512 blocks: (b, pair jp, parity v in 0..3). Block runs ranges jp and 63-jp; processes
// key-tiles tt ≡ v (mod 4). 4 waves = 4 q-subs share each staged K/V tile.
__global__ __launch_bounds__(256) void attn_kernel(
    const ushort_t* __restrict__ Qg, const ushort_t* __restrict__ Kg,
    const ushort_t* __restrict__ Vtg,
    float* __restrict__ pacc, float* __restrict__ pm, float* __restrict__ pl)
{
    __shared__ char smem[40960];   // K dbuf 16K | V dbuf 16K | P 4x2K
    const int t    = threadIdx.x;
    const int w    = t >> 6;
    const int lane = t & 63;
    const int l15  = lane & 15;
    const int l4   = lane >> 4;

    const int g     = blockIdx.x;
    const int b     = g >> 7;
    const int inner = g & 127;
    const int jp    = inner >> 2;              // pair index 0..31
    const int v     = inner & 3;               // key parity 0..3

    const ushort_t* Kb_ = Kg  + (size_t)b * S_LEN * HS;
    const ushort_t* Vb_ = Vtg + (size_t)b * HS * S_LEN;
    const ushort_t* Qb_ = Qg  + (size_t)b * S_LEN * HS;

    char* myP = smem + 32768 + w * 2048;       // P[16 q][64 k] bf16
    const int psw = (l15 & 7) << 4;

    auto stage = [&](int k0, int db) {
#pragma unroll
        for (int i = 0; i < 2; ++i) {
            const int row = w * 16 + i * 8 + (lane >> 3);
            const int c   = lane & 7;
            gl_lds16(Kb_ + (size_t)(k0 + row) * HS + ((c ^ (row & 7)) * 8),
                     smem + db * 8192 + w * 2048 + i * 1024);
            gl_lds16(Vb_ + (size_t)row * S_LEN + k0 + ((c ^ (row & 7)) * 8),
                     smem + 16384 + db * 8192 + w * 2048 + i * 1024);
        }
    };

    auto run_phase = [&](int r, int pidx) {
        const int q0r = r * BK;
        const int nt  = r + 1;
        const int q   = q0r + w * 16 + l15;
        const ushort_t* qrow = Qb_ + (size_t)q * HS;
        short8 qf0 = *(const short8*)(qrow + l4 * 8);
        short8 qf1 = *(const short8*)(qrow + 32 + l4 * 8);
        f32x4 acc[4];
#pragma unroll
        for (int j = 0; j < 4; ++j) acc[j] = (f32x4){0.f,0.f,0.f,0.f};
        float mm = -3e38f, ls = 0.f;

        __syncthreads();                       // prior-phase readers done
        if (v < nt) stage(v * BK, 0);
        int db = 0;
        for (int tt = v; tt < nt; tt += 4, db ^= 1) {
            __syncthreads();                   // staged(tt) complete (vmcnt drain)
            if (tt + 4 < nt) stage((tt + 4) * BK, db ^ 1);
            const char* Kt  = smem + db * 8192;
            const char* Vt2 = smem + 16384 + db * 8192;

            f32x4 sT[4];
#pragma unroll
            for (int st = 0; st < 4; ++st) {
                const int krow = st * 16 + l15;
                const char* krb = Kt + krow * 128;
                const int sw = krow & 7;
                short8 kc0 = *(const short8*)(krb + ((l4 ^ sw) << 4));
                short8 kc1 = *(const short8*)(krb + (((4 + l4) ^ sw) << 4));
                f32x4 z = (f32x4){0.f,0.f,0.f,0.f};
                z = __builtin_amdgcn_mfma_f32_16x16x32_bf16(kc0, qf0, z, 0, 0, 0);
                z = __builtin_amdgcn_mfma_f32_16x16x32_bf16(kc1, qf1, z, 0, 0, 0);
                sT[st] = z;
            }
            if (tt == r) {                     // diagonal tile: causal mask
#pragma unroll
                for (int st = 0; st < 4; ++st)
#pragma unroll
                    for (int rr = 0; rr < 4; ++rr)
                        if (tt * BK + st * 16 + l4 * 4 + rr > q) sT[st][rr] = -3e38f;
            }
            float a0 = fmaxf(fmaxf(sT[0][0], sT[0][1]), fmaxf(sT[0][2], sT[0][3]));
            float a1 = fmaxf(fmaxf(sT[1][0], sT[1][1]), fmaxf(sT[1][2], sT[1][3]));
            float a2 = fmaxf(fmaxf(sT[2][0], sT[2][1]), fmaxf(sT[2][2], sT[2][3]));
            float a3 = fmaxf(fmaxf(sT[3][0], sT[3][1]), fmaxf(sT[3][2], sT[3][3]));
            float mt = fmaxf(fmaxf(a0, a1), fmaxf(a2, a3));
            if (__any(mt > mm + 8.f)) {        // rare: full max + rescale
                mt = fmaxf(mt, __shfl_xor(mt, 16));
                mt = fmaxf(mt, __shfl_xor(mt, 32));
                float mn = fmaxf(mm, mt);
                float corr = __expf(mm - mn);
                ls *= corr;
#pragma unroll
                for (int ds = 0; ds < 4; ++ds)
#pragma unroll
                    for (int rr = 0; rr < 4; ++rr) acc[ds][rr] *= corr;
                mm = mn;
            }
            char* pr = myP + l15 * 128;
            float la = 0.f;
#pragma unroll
            for (int st = 0; st < 4; ++st) {
                float p0 = __expf(sT[st][0] - mm);
                float p1 = __expf(sT[st][1] - mm);
                float p2 = __expf(sT[st][2] - mm);
                float p3 = __expf(sT[st][3] - mm);
                la += (p0 + p1) + (p2 + p3);
                uint2 pk; pk.x = cvt_pk_bf16(p0, p1); pk.y = cvt_pk_bf16(p2, p3);
                *(uint2*)(pr + ((st * 32 + l4 * 8) ^ psw)) = pk;
            }
            ls += la;
            short8 pb0 = *(const short8*)(pr + ((l4 * 16) ^ psw));
            short8 pb1 = *(const short8*)(pr + ((64 + l4 * 16) ^ psw));
#pragma unroll
            for (int ds = 0; ds < 4; ++ds) {
                const int vrow = ds * 16 + l15;
                const char* vrb = Vt2 + vrow * 128;
                const int sw2 = vrow & 7;
                short8 v0 = *(const short8*)(vrb + ((l4 ^ sw2) << 4));
                short8 v1 = *(const short8*)(vrb + (((4 + l4) ^ sw2) << 4));
                acc[ds] = __builtin_amdgcn_mfma_f32_16x16x32_bf16(v0, pb0, acc[ds], 0, 0, 0);
                acc[ds] = __builtin_amdgcn_mfma_f32_16x16x32_bf16(v1, pb1, acc[ds], 0, 0, 0);
            }
        }

        ls += __shfl_xor(ls, 16);
        ls += __shfl_xor(ls, 32);
        float* pa = pacc + ((size_t)pidx * 64 + w * 16 + l15) * 64 + l4 * 4;
#pragma unroll
        for (int ds = 0; ds < 4; ++ds) *(f32x4*)(pa + ds * 16) = acc[ds];
        if (l4 == 0) {
            pm[pidx * 64 + w * 16 + l15] = mm;
            pl[pidx * 64 + w * 16 + l15] = ls;
        }
    };

    run_phase(jp,      (b * 64 + jp) * 4 + v);
    run_phase(63 - jp, (b * 64 + 63 - jp) * 4 + v);
}

// ---------------- Stage 2: combine the 4 parity partials per 64-row range -------------
__global__ __launch_bounds__(256) void combine_kernel(
    const float* __restrict__ pacc, const float* __restrict__ pm, const float* __restrict__ pl,
    float* __restrict__ out)
{
    const int g   = blockIdx.x;        // b*64 + r
    const int t   = threadIdx.x;
    const int row = t >> 2;            // 0..63
    const int d0  = (t & 3) * 16;
    float mv[4], lv[4];
#pragma unroll
    for (int p = 0; p < 4; ++p) {
        mv[p] = pm[(g * 4 + p) * 64 + row];
        lv[p] = pl[(g * 4 + p) * 64 + row];
    }
    float ms = fmaxf(fmaxf(mv[0], mv[1]), fmaxf(mv[2], mv[3]));
    float e[4], ll = 0.f;
#pragma unroll
    for (int p = 0; p < 4; ++p) { e[p] = __expf(mv[p] - ms); ll += lv[p] * e[p]; }
    const float inv = 1.f / ll;
    float4* op = (float4*)&out[((size_t)g * 64 + row) * 64 + d0];
#pragma unroll
    for (int i = 0; i < 4; ++i) {
        float4 o = make_float4(0.f, 0.f, 0.f, 0.f);
#pragma unroll
        for (int p = 0; p < 4; ++p) {
            float4 a = *(const float4*)&pacc[((size_t)(g * 4 + p) * 64 + row) * 64 + d0 + i * 4];
            o.x += a.x * e[p]; o.y += a.y * e[p]; o.z += a.z * e[p]; o.w += a.w * e[p];
        }
        op[i] = make_float4(o.x * inv, o.y * inv, o.z * inv, o.w * inv);
    }
}

extern "C" void kernel_launch(void* const* d_in, const int* in_sizes, int n_in,
                              void* d_out, int out_size, void* d_ws, size_t ws_size,
                              hipStream_t stream) {
    const float* x  = (const float*)d_in[0];
    const float* Wq = (const float*)d_in[1];
    const float* Wk = (const float*)d_in[2];
    const float* Wv = (const float*)d_in[3];
    float* out = (float*)d_out;

    const int rows = in_sizes[0] / EMBD;   // B*S = 16384
    const int B    = rows / S_LEN;         // 4

    ushort_t* Qb = (ushort_t*)d_ws;
    ushort_t* Kb = Qb + (size_t)rows * HS;
    ushort_t* Vt = Kb + (size_t)rows * HS;
    ushort_t* Wt = Vt + (size_t)rows * HS;
    float* pacc = (float*)(Wt + 192 * EMBD);                 // [B*64*4][64][64] f32 ~17MB
    float* pm   = pacc + (size_t)B * 64 * 4 * 64 * 64;
    float* pl   = pm + (size_t)B * 64 * 4 * 64;

    hipLaunchKernelGGL(wprep_kernel, dim3(36), dim3(256), 0, stream, Wq, Wk, Wv, Wt);
    hipLaunchKernelGGL(qkv_kernel, dim3(rows / 32), dim3(512), 0, stream,
                       x, Wt, Qb, Kb, Vt);
    hipLaunchKernelGGL(attn_kernel, dim3(B * 128), dim3(256), 0, stream,
                       Qb, Kb, Vt, pacc, pm, pl);
    hipLaunchKernelGGL(combine_kernel, dim3(B * 64), dim3(256), 0, stream,
                       pacc, pm, pl, out);
}

// Round 10
// 56.649 us; speedup vs baseline: 3.4929x; 1.3363x over previous
//
#include <hip/hip_runtime.h>

#define EMBD 768
#define HS 64
#define S_LEN 4096
#define BK 64

typedef __attribute__((ext_vector_type(8))) short short8;
typedef __attribute__((ext_vector_type(4))) short short4_t;
typedef __attribute__((ext_vector_type(4))) float f32x4;
typedef unsigned short ushort_t;
typedef unsigned int uint_t;

static __device__ __forceinline__ ushort_t f2bf(float f) {
    union { float f; unsigned u; } x; x.f = f;
    unsigned r = x.u + 0x7fffu + ((x.u >> 16) & 1u);   // RNE
    return (ushort_t)(r >> 16);
}

static __device__ __forceinline__ uint_t cvt_pk_bf16(float lo, float hi) {
    uint_t r;
    asm volatile("v_cvt_pk_bf16_f32 %0, %1, %2" : "=v"(r) : "v"(lo), "v"(hi));
    return r;
}

static __device__ __forceinline__ short8 pack_bf8(float4 a, float4 b) {
    union { short8 s; uint_t u[4]; } r;
    r.u[0] = cvt_pk_bf16(a.x, a.y); r.u[1] = cvt_pk_bf16(a.z, a.w);
    r.u[2] = cvt_pk_bf16(b.x, b.y); r.u[3] = cvt_pk_bf16(b.z, b.w);
    return r.s;
}

static __device__ __forceinline__ void gl_lds16(const void* g, void* l) {
    __builtin_amdgcn_global_load_lds(
        (const __attribute__((address_space(1))) unsigned int*)g,
        (__attribute__((address_space(3))) unsigned int*)l, 16, 0, 0);
}

// ---------------- W prep: Wt[192][768] bf16, Wt[c][k] = W_sel[k][c%64] ----------------
__global__ __launch_bounds__(256) void wprep_kernel(
    const float* __restrict__ Wq, const float* __restrict__ Wk, const float* __restrict__ Wv,
    ushort_t* __restrict__ Wt)
{
    __shared__ float ws[64][65];
    const int blk  = blockIdx.x;           // 36 = 3 W x 12 k-blocks
    const int widx = blk / 12, kblk = blk % 12;
    const float* W = (widx == 0) ? Wq : (widx == 1) ? Wk : Wv;
    const int k0 = kblk * 64;
    const int t  = threadIdx.x;
    const int r  = t >> 2, c0 = (t & 3) * 16;
#pragma unroll
    for (int i = 0; i < 4; ++i) {
        float4 v = *(const float4*)(W + (size_t)(k0 + r) * HS + c0 + i * 4);
        ws[c0 + i*4 + 0][r] = v.x; ws[c0 + i*4 + 1][r] = v.y;
        ws[c0 + i*4 + 2][r] = v.z; ws[c0 + i*4 + 3][r] = v.w;
    }
    __syncthreads();
    const int c = t >> 2, kc = (t & 3) * 16;
    ushort_t* dst = Wt + (size_t)(widx * 64 + c) * EMBD + k0 + kc;
#pragma unroll
    for (int i = 0; i < 4; ++i) {
        short4_t p = {(short)f2bf(ws[c][kc + i*4 + 0]), (short)f2bf(ws[c][kc + i*4 + 1]),
                      (short)f2bf(ws[c][kc + i*4 + 2]), (short)f2bf(ws[c][kc + i*4 + 3])};
        *(short4_t*)(dst + i * 4) = p;
    }
}

// ---------------- QKV via MFMA: A AND W both gl_lds-staged (m97 structure) -------------
// 256 blocks (1/CU) x 512 thr (8 waves = 2 mg x 4 cg). Tile 64 rows x 192 cols, BK=64.
// LDS: A fp32 [64][64] dbuf (16KB ea, granule16 ^ (row&15)); W bf16 [192][64] dbuf
// (24KB ea, granule16 ^ (c&7)). Loop = stage(next) ; ds_read+MFMA(cur) ; barrier.
__global__ __launch_bounds__(512) void qkv_kernel(
    const float* __restrict__ x, const ushort_t* __restrict__ Wt,
    ushort_t* __restrict__ Qg, ushort_t* __restrict__ Kg, ushort_t* __restrict__ Vtg)
{
    __shared__ char xA[2][16384];              // fp32 A tile
    __shared__ char Wl[2][24576];              // bf16 W tile
    __shared__ float Vs[64][65];
    const int t    = threadIdx.x;
    const int w    = t >> 6;
    const int lane = t & 63;
    const int l15  = lane & 15;
    const int l4   = lane >> 4;
    const int mg   = w >> 2;                   // 0..1 row-group (32 rows)
    const int cg   = w & 3;                    // 0..3 col-group (48 cols)
    const int row0 = blockIdx.x * 64;

    // ---- staging maps (linear LDS dest, pre-swizzled global source)
    // A: 1024 granule16 per buf; idx = j*512+t; row=idx>>4, g=idx&15; content g^(row&15)
    const int arow_s0 = t >> 4,          ag0 = t & 15;
    const int arow_s1 = (512 + t) >> 4,  ag1 = t & 15;        // (512+t)&15 == t&15
    const float* asrc0 = x + (size_t)(row0 + arow_s0) * EMBD + ((ag0 ^ (arow_s0 & 15)) << 2);
    const float* asrc1 = x + (size_t)(row0 + arow_s1) * EMBD + ((ag1 ^ (arow_s1 & 15)) << 2);
    // W: 1536 granule16 per buf; idx = j*512+t; c=idx>>3, g=idx&7; content g^(c&7)
    const int wc0 = t >> 3,           wg0 = t & 7;
    const int wc1 = (512 + t) >> 3,   wg1 = t & 7;
    const int wc2 = (1024 + t) >> 3,  wg2 = t & 7;
    const ushort_t* wsrc0 = Wt + (size_t)wc0 * EMBD + ((wg0 ^ (wc0 & 7)) << 3);
    const ushort_t* wsrc1 = Wt + (size_t)wc1 * EMBD + ((wg1 ^ (wc1 & 7)) << 3);
    const ushort_t* wsrc2 = Wt + (size_t)wc2 * EMBD + ((wg2 ^ (wc2 & 7)) << 3);

    auto stage = [&](int kt, int buf) {
        const int xo = kt * 64;                // floats / bf16 offset along k
        gl_lds16(asrc0 + xo, xA[buf] + w * 1024);
        gl_lds16(asrc1 + xo, xA[buf] + 8192 + w * 1024);
        gl_lds16(wsrc0 + xo, Wl[buf] + w * 1024);
        gl_lds16(wsrc1 + xo, Wl[buf] + 8192 + w * 1024);
        gl_lds16(wsrc2 + xo, Wl[buf] + 16384 + w * 1024);
    };

    // ---- read addresses
    const int ar0 = mg * 32 + l15;             // rf=0 A row
    const int ar1 = mg * 32 + 16 + l15;        // rf=1
    const int wcol0 = cg * 48 + l15;           // ct=0 W row (col)
    const int wcol1 = cg * 48 + 16 + l15;
    const int wcol2 = cg * 48 + 32 + l15;

    f32x4 acc[2][3];
#pragma unroll
    for (int i = 0; i < 2; ++i)
#pragma unroll
        for (int j = 0; j < 3; ++j) acc[i][j] = (f32x4){0.f, 0.f, 0.f, 0.f};

    stage(0, 0);
    __syncthreads();

#pragma unroll
    for (int kt = 0; kt < 12; ++kt) {
        const int cur = kt & 1;
        if (kt < 11) stage(kt + 1, cur ^ 1);
        const char* Ab = xA[cur];
        const char* Wb = Wl[cur];
#pragma unroll
        for (int ks = 0; ks < 2; ++ks) {
            // A fragments (fp32 -> bf16 in-register)
            const int gf = ks * 8 + l4 * 2;
            float4 a00 = *(const float4*)(Ab + ar0 * 256 + (((gf    ) ^ (ar0 & 15)) << 4));
            float4 a01 = *(const float4*)(Ab + ar0 * 256 + (((gf + 1) ^ (ar0 & 15)) << 4));
            float4 a10 = *(const float4*)(Ab + ar1 * 256 + (((gf    ) ^ (ar1 & 15)) << 4));
            float4 a11 = *(const float4*)(Ab + ar1 * 256 + (((gf + 1) ^ (ar1 & 15)) << 4));
            short8 af0 = pack_bf8(a00, a01);
            short8 af1 = pack_bf8(a10, a11);
            // W fragments
            const int gw = ks * 4 + l4;
            short8 wf0 = *(const short8*)(Wb + wcol0 * 128 + ((gw ^ (wcol0 & 7)) << 4));
            short8 wf1 = *(const short8*)(Wb + wcol1 * 128 + ((gw ^ (wcol1 & 7)) << 4));
            short8 wf2 = *(const short8*)(Wb + wcol2 * 128 + ((gw ^ (wcol2 & 7)) << 4));
            acc[0][0] = __builtin_amdgcn_mfma_f32_16x16x32_bf16(af0, wf0, acc[0][0], 0, 0, 0);
            acc[0][1] = __builtin_amdgcn_mfma_f32_16x16x32_bf16(af0, wf1, acc[0][1], 0, 0, 0);
            acc[0][2] = __builtin_amdgcn_mfma_f32_16x16x32_bf16(af0, wf2, acc[0][2], 0, 0, 0);
            acc[1][0] = __builtin_amdgcn_mfma_f32_16x16x32_bf16(af1, wf0, acc[1][0], 0, 0, 0);
            acc[1][1] = __builtin_amdgcn_mfma_f32_16x16x32_bf16(af1, wf1, acc[1][1], 0, 0, 0);
            acc[1][2] = __builtin_amdgcn_mfma_f32_16x16x32_bf16(af1, wf2, acc[1][2], 0, 0, 0);
        }
        if (kt < 11) __syncthreads();
    }

    // ---- epilogue: Q (pre-scaled 1/8) / K direct; V via Vs transpose
#pragma unroll
    for (int rf = 0; rf < 2; ++rf) {
        const int lrow = mg * 32 + rf * 16 + l4 * 4;
        const size_t grow = (size_t)row0 + lrow;
#pragma unroll
        for (int ct = 0; ct < 3; ++ct) {
            const int cbase = cg * 48 + ct * 16;
            const int sel   = cbase >> 6;              // 0=Q 1=K 2=V (uniform per ct)
            const int cloc  = (cbase & 63) + l15;
#pragma unroll
            for (int r = 0; r < 4; ++r) {
                const float v = acc[rf][ct][r];
                if (sel == 0)      Qg[(grow + r) * HS + cloc] = f2bf(v * 0.125f);
                else if (sel == 1) Kg[(grow + r) * HS + cloc] = f2bf(v);
                else               Vs[lrow + r][cloc] = v;
            }
        }
    }
    __syncthreads();
    // Vt write: thread t -> col t>>3, rows (t&7)*8..+7
    {
        const int vcol = t >> 3, vr0 = (t & 7) * 8;
        const int bb = row0 >> 12, s0 = row0 & 4095;
        union { short8 s; uint_t u[4]; } vp;
#pragma unroll
        for (int i = 0; i < 4; ++i)
            vp.u[i] = cvt_pk_bf16(Vs[vr0 + i * 2][vcol], Vs[vr0 + i * 2 + 1][vcol]);
        *(short8*)(Vtg + ((size_t)bb * HS + vcol) * S_LEN + s0 + vr0) = vp.s;
    }
}

// ---------------- Flash attention: 64-q-row blocks, 4-way key parity ------------------
__global__ __launch_bounds__(256) void attn_kernel(
    const ushort_t* __restrict__ Qg, const ushort_t* __restrict__ Kg,
    const ushort_t* __restrict__ Vtg,
    float* __restrict__ pacc, float* __restrict__ pm, float* __restrict__ pl)
{
    __shared__ char smem[40960];   // K dbuf 16K | V dbuf 16K | P 4x2K
    const int t    = threadIdx.x;
    const int w    = t >> 6;
    const int lane = t & 63;
    const int l15  = lane & 15;
    const int l4   = lane >> 4;

    const int g     = blockIdx.x;
    const int b     = g >> 7;
    const int inner = g & 127;
    const int jp    = inner >> 2;              // pair index 0..31
    const int v     = inner & 3;               // key parity 0..3

    const ushort_t* Kb_ = Kg  + (size_t)b * S_LEN * HS;
    const ushort_t* Vb_ = Vtg + (size_t)b * HS * S_LEN;
    const ushort_t* Qb_ = Qg  + (size_t)b * S_LEN * HS;

    char* myP = smem + 32768 + w * 2048;       // P[16 q][64 k] bf16
    const int psw = (l15 & 7) << 4;

    auto stage = [&](int k0, int db) {
#pragma unroll
        for (int i = 0; i < 2; ++i) {
            const int row = w * 16 + i * 8 + (lane >> 3);
            const int c   = lane & 7;
            gl_lds16(Kb_ + (size_t)(k0 + row) * HS + ((c ^ (row & 7)) * 8),
                     smem + db * 8192 + w * 2048 + i * 1024);
            gl_lds16(Vb_ + (size_t)row * S_LEN + k0 + ((c ^ (row & 7)) * 8),
                     smem + 16384 + db * 8192 + w * 2048 + i * 1024);
        }
    };

    auto run_phase = [&](int r, int pidx) {
        const int q0r = r * BK;
        const int nt  = r + 1;
        const int q   = q0r + w * 16 + l15;
        const ushort_t* qrow = Qb_ + (size_t)q * HS;
        short8 qf0 = *(const short8*)(qrow + l4 * 8);
        short8 qf1 = *(const short8*)(qrow + 32 + l4 * 8);
        f32x4 acc[4];
#pragma unroll
        for (int j = 0; j < 4; ++j) acc[j] = (f32x4){0.f,0.f,0.f,0.f};
        float mm = -3e38f, ls = 0.f;

        __syncthreads();                       // prior-phase readers done
        if (v < nt) stage(v * BK, 0);
        int db = 0;
        for (int tt = v; tt < nt; tt += 4, db ^= 1) {
            __syncthreads();                   // staged(tt) complete (vmcnt drain)
            if (tt + 4 < nt) stage((tt + 4) * BK, db ^ 1);
            const char* Kt  = smem + db * 8192;
            const char* Vt2 = smem + 16384 + db * 8192;

            f32x4 sT[4];
#pragma unroll
            for (int st = 0; st < 4; ++st) {
                const int krow = st * 16 + l15;
                const char* krb = Kt + krow * 128;
                const int sw = krow & 7;
                short8 kc0 = *(const short8*)(krb + ((l4 ^ sw) << 4));
                short8 kc1 = *(const short8*)(krb + (((4 + l4) ^ sw) << 4));
                f32x4 z = (f32x4){0.f,0.f,0.f,0.f};
                z = __builtin_amdgcn_mfma_f32_16x16x32_bf16(kc0, qf0, z, 0, 0, 0);
                z = __builtin_amdgcn_mfma_f32_16x16x32_bf16(kc1, qf1, z, 0, 0, 0);
                sT[st] = z;
            }
            if (tt == r) {                     // diagonal tile: causal mask
#pragma unroll
                for (int st = 0; st < 4; ++st)
#pragma unroll
                    for (int rr = 0; rr < 4; ++rr)
                        if (tt * BK + st * 16 + l4 * 4 + rr > q) sT[st][rr] = -3e38f;
            }
            float a0 = fmaxf(fmaxf(sT[0][0], sT[0][1]), fmaxf(sT[0][2], sT[0][3]));
            float a1 = fmaxf(fmaxf(sT[1][0], sT[1][1]), fmaxf(sT[1][2], sT[1][3]));
            float a2 = fmaxf(fmaxf(sT[2][0], sT[2][1]), fmaxf(sT[2][2], sT[2][3]));
            float a3 = fmaxf(fmaxf(sT[3][0], sT[3][1]), fmaxf(sT[3][2], sT[3][3]));
            float mt = fmaxf(fmaxf(a0, a1), fmaxf(a2, a3));
            if (__any(mt > mm + 8.f)) {        // rare: full max + rescale
                mt = fmaxf(mt, __shfl_xor(mt, 16));
                mt = fmaxf(mt, __shfl_xor(mt, 32));
                float mn = fmaxf(mm, mt);
                float corr = __expf(mm - mn);
                ls *= corr;
#pragma unroll
                for (int ds = 0; ds < 4; ++ds)
#pragma unroll
                    for (int rr = 0; rr < 4; ++rr) acc[ds][rr] *= corr;
                mm = mn;
            }
            char* pr = myP + l15 * 128;
            float la = 0.f;
#pragma unroll
            for (int st = 0; st < 4; ++st) {
                float p0 = __expf(sT[st][0] - mm);
                float p1 = __expf(sT[st][1] - mm);
                float p2 = __expf(sT[st][2] - mm);
                float p3 = __expf(sT[st][3] - mm);
                la += (p0 + p1) + (p2 + p3);
                uint2 pk; pk.x = cvt_pk_bf16(p0, p1); pk.y = cvt_pk_bf16(p2, p3);
                *(uint2*)(pr + ((st * 32 + l4 * 8) ^ psw)) = pk;
            }
            ls += la;
            short8 pb0 = *(const short8*)(pr + ((l4 * 16) ^ psw));
            short8 pb1 = *(const short8*)(pr + ((64 + l4 * 16) ^ psw));
#pragma unroll
            for (int ds = 0; ds < 4; ++ds) {
                const int vrow = ds * 16 + l15;
                const char* vrb = Vt2 + vrow * 128;
                const int sw2 = vrow & 7;
                short8 v0 = *(const short8*)(vrb + ((l4 ^ sw2) << 4));
                short8 v1 = *(const short8*)(vrb + (((4 + l4) ^ sw2) << 4));
                acc[ds] = __builtin_amdgcn_mfma_f32_16x16x32_bf16(v0, pb0, acc[ds], 0, 0, 0);
                acc[ds] = __builtin_amdgcn_mfma_f32_16x16x32_bf16(v1, pb1, acc[ds], 0, 0, 0);
            }
        }

        ls += __shfl_xor(ls, 16);
        ls += __shfl_xor(ls, 32);
        float* pa = pacc + ((size_t)pidx * 64 + w * 16 + l15) * 64 + l4 * 4;
#pragma unroll
        for (int ds = 0; ds < 4; ++ds) *(f32x4*)(pa + ds * 16) = acc[ds];
        if (l4 == 0) {
            pm[pidx * 64 + w * 16 + l15] = mm;
            pl[pidx * 64 + w * 16 + l15] = ls;
        }
    };

    run_phase(jp,      (b * 64 + jp) * 4 + v);
    run_phase(63 - jp, (b * 64 + 63 - jp) * 4 + v);
}

// ---------------- Stage 2: combine the 4 parity partials per 64-row range -------------
__global__ __launch_bounds__(256) void combine_kernel(
    const float* __restrict__ pacc, const float* __restrict__ pm, const float* __restrict__ pl,
    float* __restrict__ out)
{
    const int g   = blockIdx.x;        // b*64 + r
    const int t   = threadIdx.x;
    const int row = t >> 2;            // 0..63
    const int d0  = (t & 3) * 16;
    float mv[4], lv[4];
#pragma unroll
    for (int p = 0; p < 4; ++p) {
        mv[p] = pm[(g * 4 + p) * 64 + row];
        lv[p] = pl[(g * 4 + p) * 64 + row];
    }
    float ms = fmaxf(fmaxf(mv[0], mv[1]), fmaxf(mv[2], mv[3]));
    float e[4], ll = 0.f;
#pragma unroll
    for (int p = 0; p < 4; ++p) { e[p] = __expf(mv[p] - ms); ll += lv[p] * e[p]; }
    const float inv = 1.f / ll;
    float4* op = (float4*)&out[((size_t)g * 64 + row) * 64 + d0];
#pragma unroll
    for (int i = 0; i < 4; ++i) {
        float4 o = make_float4(0.f, 0.f, 0.f, 0.f);
#pragma unroll
        for (int p = 0; p < 4; ++p) {
            float4 a = *(const float4*)&pacc[((size_t)(g * 4 + p) * 64 + row) * 64 + d0 + i * 4];
            o.x += a.x * e[p]; o.y += a.y * e[p]; o.z += a.z * e[p]; o.w += a.w * e[p];
        }
        op[i] = make_float4(o.x * inv, o.y * inv, o.z * inv, o.w * inv);
    }
}

extern "C" void kernel_launch(void* const* d_in, const int* in_sizes, int n_in,
                              void* d_out, int out_size, void* d_ws, size_t ws_size,
                              hipStream_t stream) {
    const float* x  = (const float*)d_in[0];
    const float* Wq = (const float*)d_in[1];
    const float* Wk = (const float*)d_in[2];
    const float* Wv = (const float*)d_in[3];
    float* out = (float*)d_out;

    const int rows = in_sizes[0] / EMBD;   // B*S = 16384
    const int B    = rows / S_LEN;         // 4

    ushort_t* Qb = (ushort_t*)d_ws;
    ushort_t* Kb = Qb + (size_t)rows * HS;
    ushort_t* Vt = Kb + (size_t)rows * HS;
    ushort_t* Wt = Vt + (size_t)rows * HS;
    float* pacc = (float*)(Wt + 192 * EMBD);                 // [B*64*4][64][64] f32 ~17MB
    float* pm   = pacc + (size_t)B * 64 * 4 * 64 * 64;
    float* pl   = pm + (size_t)B * 64 * 4 * 64;

    hipLaunchKernelGGL(wprep_kernel, dim3(36), dim3(256), 0, stream, Wq, Wk, Wv, Wt);
    hipLaunchKernelGGL(qkv_kernel, dim3(rows / 64), dim3(512), 0, stream,
                       x, Wt, Qb, Kb, Vt);
    hipLaunchKernelGGL(attn_kernel, dim3(B * 128), dim3(256), 0, stream,
                       Qb, Kb, Vt, pacc, pm, pl);
    hipLaunchKernelGGL(combine_kernel, dim3(B * 64), dim3(256), 0, stream,
                       pacc, pm, pl, out);
}

// Round 11
// 54.876 us; speedup vs baseline: 3.6058x; 1.0323x over previous
//
#include <hip/hip_runtime.h>

#define EMBD 768
#define HS 64
#define S_LEN 4096
#define BK 64

typedef __attribute__((ext_vector_type(8))) short short8;
typedef __attribute__((ext_vector_type(4))) short short4_t;
typedef __attribute__((ext_vector_type(4))) float f32x4;
typedef unsigned short ushort_t;
typedef unsigned int uint_t;

static __device__ __forceinline__ ushort_t f2bf(float f) {
    union { float f; unsigned u; } x; x.f = f;
    unsigned r = x.u + 0x7fffu + ((x.u >> 16) & 1u);   // RNE
    return (ushort_t)(r >> 16);
}

static __device__ __forceinline__ float bf2f(ushort_t u) {
    union { float f; uint_t u; } x; x.u = ((uint_t)u) << 16; return x.f;
}

static __device__ __forceinline__ uint_t cvt_pk_bf16(float lo, float hi) {
    uint_t r;
    asm volatile("v_cvt_pk_bf16_f32 %0, %1, %2" : "=v"(r) : "v"(lo), "v"(hi));
    return r;
}

static __device__ __forceinline__ short8 pack_bf8(float4 a, float4 b) {
    union { short8 s; uint_t u[4]; } r;
    r.u[0] = cvt_pk_bf16(a.x, a.y); r.u[1] = cvt_pk_bf16(a.z, a.w);
    r.u[2] = cvt_pk_bf16(b.x, b.y); r.u[3] = cvt_pk_bf16(b.z, b.w);
    return r.s;
}

static __device__ __forceinline__ void gl_lds16(const void* g, void* l) {
    __builtin_amdgcn_global_load_lds(
        (const __attribute__((address_space(1))) unsigned int*)g,
        (__attribute__((address_space(3))) unsigned int*)l, 16, 0, 0);
}

// ---------------- W prep: Wt[192][768] bf16, Wt[c][k] = W_sel[k][c%64] ----------------
__global__ __launch_bounds__(256) void wprep_kernel(
    const float* __restrict__ Wq, const float* __restrict__ Wk, const float* __restrict__ Wv,
    ushort_t* __restrict__ Wt)
{
    __shared__ float ws[64][65];
    const int blk  = blockIdx.x;           // 36 = 3 W x 12 k-blocks
    const int widx = blk / 12, kblk = blk % 12;
    const float* W = (widx == 0) ? Wq : (widx == 1) ? Wk : Wv;
    const int k0 = kblk * 64;
    const int t  = threadIdx.x;
    const int r  = t >> 2, c0 = (t & 3) * 16;
#pragma unroll
    for (int i = 0; i < 4; ++i) {
        float4 v = *(const float4*)(W + (size_t)(k0 + r) * HS + c0 + i * 4);
        ws[c0 + i*4 + 0][r] = v.x; ws[c0 + i*4 + 1][r] = v.y;
        ws[c0 + i*4 + 2][r] = v.z; ws[c0 + i*4 + 3][r] = v.w;
    }
    __syncthreads();
    const int c = t >> 2, kc = (t & 3) * 16;
    ushort_t* dst = Wt + (size_t)(widx * 64 + c) * EMBD + k0 + kc;
#pragma unroll
    for (int i = 0; i < 4; ++i) {
        short4_t p = {(short)f2bf(ws[c][kc + i*4 + 0]), (short)f2bf(ws[c][kc + i*4 + 1]),
                      (short)f2bf(ws[c][kc + i*4 + 2]), (short)f2bf(ws[c][kc + i*4 + 3])};
        *(short4_t*)(dst + i * 4) = p;
    }
}

// ---------------- QKV via MFMA: 32-row x BK=32 tiles, gl_lds dbuf, 2-3 blocks/CU -------
// 512 blocks x 512 thr (8 waves = 2 mg x 4 cg). LDS: A fp32 [32][32] dbuf (4KB ea,
// granule16 ^ (row&7)); W bf16 [192][32] dbuf (12KB ea, granule16 ^ ((c&3)^((c>>2)&3))).
__global__ __launch_bounds__(512) void qkv_kernel(
    const float* __restrict__ x, const ushort_t* __restrict__ Wt,
    ushort_t* __restrict__ Qg, ushort_t* __restrict__ Kg, ushort_t* __restrict__ Vtg)
{
    __shared__ char xA[2][4096];               // fp32 A tile [32 rows][32 k]
    __shared__ char Wl[2][12288];              // bf16 W tile [192 c][32 k]
    __shared__ float Vs[32][65];
    const int t    = threadIdx.x;
    const int w    = t >> 6;
    const int lane = t & 63;
    const int l15  = lane & 15;
    const int l4   = lane >> 4;
    const int mg   = w >> 2;                   // 0..1 (16 rows each)
    const int cg   = w & 3;                    // 0..3 (48 cols each)
    const int row0 = blockIdx.x * 32;

    // ---- staging maps (linear LDS dest, pre-swizzled global source)
    // g1: t<256 -> A granule t (row=t>>3, gi=t&7, content gi^(row&7));
    //     t>=256 -> W granule t-256 (c=(t-256)>>2, gi=t&3, content gi^sc(c))
    // g2: all t -> W granule 256+t (c=64+(t>>2), gi=t&3)
    const float* g1srcA = 0; const ushort_t* g1srcW = 0;
    if (t < 256) {
        const int row = t >> 3, gi = t & 7;
        g1srcA = x + (size_t)(row0 + row) * EMBD + ((gi ^ (row & 7)) << 2);
    } else {
        const int c = (t - 256) >> 2, gi = t & 3;
        const int sc = (c & 3) ^ ((c >> 2) & 3);
        g1srcW = Wt + (size_t)c * EMBD + ((gi ^ sc) << 3);
    }
    const int c2 = 64 + (t >> 2), gi2 = t & 3;
    const int sc2 = (c2 & 3) ^ ((c2 >> 2) & 3);
    const ushort_t* g2srcW = Wt + (size_t)c2 * EMBD + ((gi2 ^ sc2) << 3);

    auto stage = [&](int kt, int buf) {
        const int xo = kt * 32;                // elements along k
        if (t < 256) gl_lds16(g1srcA + xo, xA[buf] + (w & 3) * 1024);
        else         gl_lds16(g1srcW + xo, Wl[buf] + (w - 4) * 1024);
        gl_lds16(g2srcW + xo, Wl[buf] + 4096 + w * 1024);
    };

    // ---- read addresses
    const int ar = mg * 16 + l15;              // A row
    const int wc0 = cg * 48 + l15;             // W cols for ct=0,1,2
    const int wc1 = wc0 + 16, wc2 = wc0 + 32;
    const int swc0 = l4 ^ (wc0 & 3) ^ ((wc0 >> 2) & 3);
    const int swc1 = l4 ^ (wc1 & 3) ^ ((wc1 >> 2) & 3);
    const int swc2 = l4 ^ (wc2 & 3) ^ ((wc2 >> 2) & 3);

    f32x4 acc[3];
#pragma unroll
    for (int j = 0; j < 3; ++j) acc[j] = (f32x4){0.f, 0.f, 0.f, 0.f};

    stage(0, 0);
    __syncthreads();

#pragma unroll
    for (int kt = 0; kt < 24; ++kt) {
        const int cur = kt & 1;
        if (kt < 23) stage(kt + 1, cur ^ 1);
        const char* Ab = xA[cur];
        const char* Wb = Wl[cur];
        // A fragment: fp32 granules 2*l4, 2*l4+1 of row ar, swizzled ^(ar&7)
        float4 a0 = *(const float4*)(Ab + ar * 128 + (((2 * l4)     ^ (ar & 7)) << 4));
        float4 a1 = *(const float4*)(Ab + ar * 128 + (((2 * l4 + 1) ^ (ar & 7)) << 4));
        short8 af = pack_bf8(a0, a1);
        short8 wf0 = *(const short8*)(Wb + wc0 * 64 + (swc0 << 4));
        short8 wf1 = *(const short8*)(Wb + wc1 * 64 + (swc1 << 4));
        short8 wf2 = *(const short8*)(Wb + wc2 * 64 + (swc2 << 4));
        acc[0] = __builtin_amdgcn_mfma_f32_16x16x32_bf16(af, wf0, acc[0], 0, 0, 0);
        acc[1] = __builtin_amdgcn_mfma_f32_16x16x32_bf16(af, wf1, acc[1], 0, 0, 0);
        acc[2] = __builtin_amdgcn_mfma_f32_16x16x32_bf16(af, wf2, acc[2], 0, 0, 0);
        if (kt < 23) __syncthreads();
    }

    // ---- epilogue: Q (pre-scaled 1/8) / K direct; V via Vs transpose
    const int lrow = mg * 16 + l4 * 4;
    const size_t grow = (size_t)row0 + lrow;
#pragma unroll
    for (int ct = 0; ct < 3; ++ct) {
        const int cbase = cg * 48 + ct * 16;
        const int sel   = cbase >> 6;              // 0=Q 1=K 2=V (uniform per ct)
        const int cloc  = (cbase & 63) + l15;
#pragma unroll
        for (int r = 0; r < 4; ++r) {
            const float v = acc[ct][r];
            if (sel == 0)      Qg[(grow + r) * HS + cloc] = f2bf(v * 0.125f);
            else if (sel == 1) Kg[(grow + r) * HS + cloc] = f2bf(v);
            else               Vs[lrow + r][cloc] = v;
        }
    }
    __syncthreads();
    {   // Vt write: thread t -> col t>>3, rows (t&7)*4..+3
        const int vcol = t >> 3, vr0 = (t & 7) * 4;
        const int bb = row0 >> 12, s0 = row0 & 4095;
        union { short4_t s; uint_t u[2]; } vp;
        vp.u[0] = cvt_pk_bf16(Vs[vr0][vcol],     Vs[vr0 + 1][vcol]);
        vp.u[1] = cvt_pk_bf16(Vs[vr0 + 2][vcol], Vs[vr0 + 3][vcol]);
        *(short4_t*)(Vtg + ((size_t)bb * HS + vcol) * S_LEN + s0 + vr0) = vp.s;
    }
}

// ---------------- Flash attention: 64-q-row blocks, 4-way key parity ------------------
__global__ __launch_bounds__(256) void attn_kernel(
    const ushort_t* __restrict__ Qg, const ushort_t* __restrict__ Kg,
    const ushort_t* __restrict__ Vtg,
    ushort_t* __restrict__ pacc, float* __restrict__ pm, float* __restrict__ pl)
{
    __shared__ char smem[40960];   // K dbuf 16K | V dbuf 16K | P 4x2K
    const int t    = threadIdx.x;
    const int w    = t >> 6;
    const int lane = t & 63;
    const int l15  = lane & 15;
    const int l4   = lane >> 4;

    const int g     = blockIdx.x;
    const int b     = g >> 7;
    const int inner = g & 127;
    const int jp    = inner >> 2;              // pair index 0..31
    const int v     = inner & 3;               // key parity 0..3

    const ushort_t* Kb_ = Kg  + (size_t)b * S_LEN * HS;
    const ushort_t* Vb_ = Vtg + (size_t)b * HS * S_LEN;
    const ushort_t* Qb_ = Qg  + (size_t)b * S_LEN * HS;

    char* myP = smem + 32768 + w * 2048;       // P[16 q][64 k] bf16
    const int psw = (l15 & 7) << 4;

    auto stage = [&](int k0, int db) {
#pragma unroll
        for (int i = 0; i < 2; ++i) {
            const int row = w * 16 + i * 8 + (lane >> 3);
            const int c   = lane & 7;
            gl_lds16(Kb_ + (size_t)(k0 + row) * HS + ((c ^ (row & 7)) * 8),
                     smem + db * 8192 + w * 2048 + i * 1024);
            gl_lds16(Vb_ + (size_t)row * S_LEN + k0 + ((c ^ (row & 7)) * 8),
                     smem + 16384 + db * 8192 + w * 2048 + i * 1024);
        }
    };

    auto run_phase = [&](int r, int pidx) {
        const int q0r = r * BK;
        const int nt  = r + 1;
        const int q   = q0r + w * 16 + l15;
        const ushort_t* qrow = Qb_ + (size_t)q * HS;
        short8 qf0 = *(const short8*)(qrow + l4 * 8);
        short8 qf1 = *(const short8*)(qrow + 32 + l4 * 8);
        f32x4 acc[4];
#pragma unroll
        for (int j = 0; j < 4; ++j) acc[j] = (f32x4){0.f,0.f,0.f,0.f};
        float mm = -3e38f, ls = 0.f;

        __syncthreads();                       // prior-phase readers done
        if (v < nt) stage(v * BK, 0);
        int db = 0;
        for (int tt = v; tt < nt; tt += 4, db ^= 1) {
            __syncthreads();                   // staged(tt) complete (vmcnt drain)
            if (tt + 4 < nt) stage((tt + 4) * BK, db ^ 1);
            const char* Kt  = smem + db * 8192;
            const char* Vt2 = smem + 16384 + db * 8192;

            f32x4 sT[4];
#pragma unroll
            for (int st = 0; st < 4; ++st) {
                const int krow = st * 16 + l15;
                const char* krb = Kt + krow * 128;
                const int sw = krow & 7;
                short8 kc0 = *(const short8*)(krb + ((l4 ^ sw) << 4));
                short8 kc1 = *(const short8*)(krb + (((4 + l4) ^ sw) << 4));
                f32x4 z = (f32x4){0.f,0.f,0.f,0.f};
                z = __builtin_amdgcn_mfma_f32_16x16x32_bf16(kc0, qf0, z, 0, 0, 0);
                z = __builtin_amdgcn_mfma_f32_16x16x32_bf16(kc1, qf1, z, 0, 0, 0);
                sT[st] = z;
            }
            if (tt == r) {                     // diagonal tile: causal mask
#pragma unroll
                for (int st = 0; st < 4; ++st)
#pragma unroll
                    for (int rr = 0; rr < 4; ++rr)
                        if (tt * BK + st * 16 + l4 * 4 + rr > q) sT[st][rr] = -3e38f;
            }
            float a0 = fmaxf(fmaxf(sT[0][0], sT[0][1]), fmaxf(sT[0][2], sT[0][3]));
            float a1 = fmaxf(fmaxf(sT[1][0], sT[1][1]), fmaxf(sT[1][2], sT[1][3]));
            float a2 = fmaxf(fmaxf(sT[2][0], sT[2][1]), fmaxf(sT[2][2], sT[2][3]));
            float a3 = fmaxf(fmaxf(sT[3][0], sT[3][1]), fmaxf(sT[3][2], sT[3][3]));
            float mt = fmaxf(fmaxf(a0, a1), fmaxf(a2, a3));
            if (__any(mt > mm + 8.f)) {        // rare: full max + rescale
                mt = fmaxf(mt, __shfl_xor(mt, 16));
                mt = fmaxf(mt, __shfl_xor(mt, 32));
                float mn = fmaxf(mm, mt);
                float corr = __expf(mm - mn);
                ls *= corr;
#pragma unroll
                for (int ds = 0; ds < 4; ++ds)
#pragma unroll
                    for (int rr = 0; rr < 4; ++rr) acc[ds][rr] *= corr;
                mm = mn;
            }
            char* pr = myP + l15 * 128;
            float la = 0.f;
#pragma unroll
            for (int st = 0; st < 4; ++st) {
                float p0 = __expf(sT[st][0] - mm);
                float p1 = __expf(sT[st][1] - mm);
                float p2 = __expf(sT[st][2] - mm);
                float p3 = __expf(sT[st][3] - mm);
                la += (p0 + p1) + (p2 + p3);
                uint2 pk; pk.x = cvt_pk_bf16(p0, p1); pk.y = cvt_pk_bf16(p2, p3);
                *(uint2*)(pr + ((st * 32 + l4 * 8) ^ psw)) = pk;
            }
            ls += la;
            short8 pb0 = *(const short8*)(pr + ((l4 * 16) ^ psw));
            short8 pb1 = *(const short8*)(pr + ((64 + l4 * 16) ^ psw));
#pragma unroll
            for (int ds = 0; ds < 4; ++ds) {
                const int vrow = ds * 16 + l15;
                const char* vrb = Vt2 + vrow * 128;
                const int sw2 = vrow & 7;
                short8 v0 = *(const short8*)(vrb + ((l4 ^ sw2) << 4));
                short8 v1 = *(const short8*)(vrb + (((4 + l4) ^ sw2) << 4));
                acc[ds] = __builtin_amdgcn_mfma_f32_16x16x32_bf16(v0, pb0, acc[ds], 0, 0, 0);
                acc[ds] = __builtin_amdgcn_mfma_f32_16x16x32_bf16(v1, pb1, acc[ds], 0, 0, 0);
            }
        }

        ls += __shfl_xor(ls, 16);
        ls += __shfl_xor(ls, 32);
        // bf16 partials (packed pairs)
        ushort_t* pa = pacc + ((size_t)pidx * 64 + w * 16 + l15) * 64 + l4 * 4;
#pragma unroll
        for (int ds = 0; ds < 4; ++ds) {
            uint2 pk;
            pk.x = cvt_pk_bf16(acc[ds][0], acc[ds][1]);
            pk.y = cvt_pk_bf16(acc[ds][2], acc[ds][3]);
            *(uint2*)(pa + ds * 16) = pk;
        }
        if (l4 == 0) {
            pm[pidx * 64 + w * 16 + l15] = mm;
            pl[pidx * 64 + w * 16 + l15] = ls;
        }
    };

    run_phase(jp,      (b * 64 + jp) * 4 + v);
    run_phase(63 - jp, (b * 64 + 63 - jp) * 4 + v);
}

// ---------------- Stage 2: combine the 4 parity partials per 64-row range -------------
__global__ __launch_bounds__(256) void combine_kernel(
    const ushort_t* __restrict__ pacc, const float* __restrict__ pm, const float* __restrict__ pl,
    float* __restrict__ out)
{
    const int g   = blockIdx.x;        // b*64 + r
    const int t   = threadIdx.x;
    const int row = t >> 2;            // 0..63
    const int d0  = (t & 3) * 16;
    float mv[4], lv[4];
#pragma unroll
    for (int p = 0; p < 4; ++p) {
        mv[p] = pm[(g * 4 + p) * 64 + row];
        lv[p] = pl[(g * 4 + p) * 64 + row];
    }
    float ms = fmaxf(fmaxf(mv[0], mv[1]), fmaxf(mv[2], mv[3]));
    float e[4], ll = 0.f;
#pragma unroll
    for (int p = 0; p < 4; ++p) { e[p] = __expf(mv[p] - ms); ll += lv[p] * e[p]; }
    const float inv = 1.f / ll;
    float o[16];
#pragma unroll
    for (int i = 0; i < 16; ++i) o[i] = 0.f;
#pragma unroll
    for (int p = 0; p < 4; ++p) {
        const ushort_t* src = pacc + ((size_t)(g * 4 + p) * 64 + row) * 64 + d0;
        short8 s0 = *(const short8*)(src);
        short8 s1 = *(const short8*)(src + 8);
#pragma unroll
        for (int i = 0; i < 8; ++i) {
            o[i]     += bf2f((ushort_t)s0[i]) * e[p];
            o[8 + i] += bf2f((ushort_t)s1[i]) * e[p];
        }
    }
    float4* op = (float4*)&out[((size_t)g * 64 + row) * 64 + d0];
#pragma unroll
    for (int i = 0; i < 4; ++i)
        op[i] = make_float4(o[i*4] * inv, o[i*4+1] * inv, o[i*4+2] * inv, o[i*4+3] * inv);
}

extern "C" void kernel_launch(void* const* d_in, const int* in_sizes, int n_in,
                              void* d_out, int out_size, void* d_ws, size_t ws_size,
                              hipStream_t stream) {
    const float* x  = (const float*)d_in[0];
    const float* Wq = (const float*)d_in[1];
    const float* Wk = (const float*)d_in[2];
    const float* Wv = (const float*)d_in[3];
    float* out = (float*)d_out;

    const int rows = in_sizes[0] / EMBD;   // B*S = 16384
    const int B    = rows / S_LEN;         // 4

    ushort_t* Qb = (ushort_t*)d_ws;
    ushort_t* Kb = Qb + (size_t)rows * HS;
    ushort_t* Vt = Kb + (size_t)rows * HS;
    ushort_t* Wt = Vt + (size_t)rows * HS;
    ushort_t* pacc = Wt + 192 * EMBD;                        // bf16 [B*64*4][64][64] ~8.4MB
    float* pm = (float*)(pacc + (size_t)B * 64 * 4 * 64 * 64);
    float* pl = pm + (size_t)B * 64 * 4 * 64;

    hipLaunchKernelGGL(wprep_kernel, dim3(36), dim3(256), 0, stream, Wq, Wk, Wv, Wt);
    hipLaunchKernelGGL(qkv_kernel, dim3(rows / 32), dim3(512), 0, stream,
                       x, Wt, Qb, Kb, Vt);
    hipLaunchKernelGGL(attn_kernel, dim3(B * 128), dim3(256), 0, stream,
                       Qb, Kb, Vt, pacc, pm, pl);
    hipLaunchKernelGGL(combine_kernel, dim3(B * 64), dim3(256), 0, stream,
                       pacc, pm, pl, out);
}

// Round 12
// 50.729 us; speedup vs baseline: 3.9006x; 1.0818x over previous
//
#include <hip/hip_runtime.h>

#define EMBD 768
#define HS 64
#define S_LEN 4096
#define BK 64
#define NPAR 6

typedef __attribute__((ext_vector_type(8))) short short8;
typedef __attribute__((ext_vector_type(4))) short short4_t;
typedef __attribute__((ext_vector_type(4))) float f32x4;
typedef unsigned short ushort_t;
typedef unsigned int uint_t;

static __device__ __forceinline__ ushort_t f2bf(float f) {
    union { float f; unsigned u; } x; x.f = f;
    unsigned r = x.u + 0x7fffu + ((x.u >> 16) & 1u);   // RNE
    return (ushort_t)(r >> 16);
}

static __device__ __forceinline__ float bf2f(ushort_t u) {
    union { float f; uint_t u; } x; x.u = ((uint_t)u) << 16; return x.f;
}

static __device__ __forceinline__ uint_t cvt_pk_bf16(float lo, float hi) {
    uint_t r;
    asm volatile("v_cvt_pk_bf16_f32 %0, %1, %2" : "=v"(r) : "v"(lo), "v"(hi));
    return r;
}

static __device__ __forceinline__ short8 pack_bf8(float4 a, float4 b) {
    union { short8 s; uint_t u[4]; } r;
    r.u[0] = cvt_pk_bf16(a.x, a.y); r.u[1] = cvt_pk_bf16(a.z, a.w);
    r.u[2] = cvt_pk_bf16(b.x, b.y); r.u[3] = cvt_pk_bf16(b.z, b.w);
    return r.s;
}

static __device__ __forceinline__ void gl_lds16(const void* g, void* l) {
    __builtin_amdgcn_global_load_lds(
        (const __attribute__((address_space(1))) unsigned int*)g,
        (__attribute__((address_space(3))) unsigned int*)l, 16, 0, 0);
}

// ---------------- W prep: Wt[192][768] bf16, Wt[c][k] = W_sel[k][c%64] ----------------
__global__ __launch_bounds__(256) void wprep_kernel(
    const float* __restrict__ Wq, const float* __restrict__ Wk, const float* __restrict__ Wv,
    ushort_t* __restrict__ Wt)
{
    __shared__ float ws[64][65];
    const int blk  = blockIdx.x;           // 36 = 3 W x 12 k-blocks
    const int widx = blk / 12, kblk = blk % 12;
    const float* W = (widx == 0) ? Wq : (widx == 1) ? Wk : Wv;
    const int k0 = kblk * 64;
    const int t  = threadIdx.x;
    const int r  = t >> 2, c0 = (t & 3) * 16;
#pragma unroll
    for (int i = 0; i < 4; ++i) {
        float4 v = *(const float4*)(W + (size_t)(k0 + r) * HS + c0 + i * 4);
        ws[c0 + i*4 + 0][r] = v.x; ws[c0 + i*4 + 1][r] = v.y;
        ws[c0 + i*4 + 2][r] = v.z; ws[c0 + i*4 + 3][r] = v.w;
    }
    __syncthreads();
    const int c = t >> 2, kc = (t & 3) * 16;
    ushort_t* dst = Wt + (size_t)(widx * 64 + c) * EMBD + k0 + kc;
#pragma unroll
    for (int i = 0; i < 4; ++i) {
        short4_t p = {(short)f2bf(ws[c][kc + i*4 + 0]), (short)f2bf(ws[c][kc + i*4 + 1]),
                      (short)f2bf(ws[c][kc + i*4 + 2]), (short)f2bf(ws[c][kc + i*4 + 3])};
        *(short4_t*)(dst + i * 4) = p;
    }
}

// ---------------- QKV via MFMA: 32-row x BK=64, gl_lds dbuf, 2 blocks/CU ---------------
// 512 blocks x 512 thr (8 waves = 2 mg x 4 cg). LDS: A fp32 [32][64] dbuf (16KB ea,
// granule16 ^ (row&15)); W bf16 [192][64] dbuf (24KB ea, granule16 ^ (c&7)).
// 6 MFMAs per barrier.
__global__ __launch_bounds__(512) void qkv_kernel(
    const float* __restrict__ x, const ushort_t* __restrict__ Wt,
    ushort_t* __restrict__ Qg, ushort_t* __restrict__ Kg, ushort_t* __restrict__ Vtg)
{
    __shared__ char xA[2][8192];               // fp32 A tile [32 rows][64 k]
    __shared__ char Wl[2][24576];              // bf16 W tile [192 c][64 k]
    __shared__ float Vs[32][65];
    const int t    = threadIdx.x;
    const int w    = t >> 6;
    const int lane = t & 63;
    const int l15  = lane & 15;
    const int l4   = lane >> 4;
    const int mg   = w >> 2;                   // 0..1 (16 rows each)
    const int cg   = w & 3;                    // 0..3 (48 cols each)
    const int row0 = blockIdx.x * 32;

    // ---- staging maps (linear LDS dest, pre-swizzled global source)
    // A: 512 granule16/buf; thread t -> (row=t>>4, pos=t&15), content granule pos^(row&15)
    const int arow_s = t >> 4, ag = t & 15;
    const float* asrc = x + (size_t)(row0 + arow_s) * EMBD + ((ag ^ (arow_s & 15)) << 2);
    // W: 1536 granule16/buf; chunk j: idx=j*512+t -> (c=idx>>3, pos=idx&7), content pos^(c&7)
    const int wcs = t >> 3, wgs = t & 7;
    const ushort_t* wsrc0 = Wt + (size_t)(wcs      ) * EMBD + ((wgs ^ (wcs & 7)) << 3);
    const ushort_t* wsrc1 = Wt + (size_t)(wcs +  64) * EMBD + ((wgs ^ (wcs & 7)) << 3);
    const ushort_t* wsrc2 = Wt + (size_t)(wcs + 128) * EMBD + ((wgs ^ (wcs & 7)) << 3);

    auto stage = [&](int kt, int buf) {
        const int xo = kt * 64;                // elements along k
        gl_lds16(asrc + xo,  xA[buf] + w * 1024);
        gl_lds16(wsrc0 + xo, Wl[buf] + w * 1024);
        gl_lds16(wsrc1 + xo, Wl[buf] + 8192 + w * 1024);
        gl_lds16(wsrc2 + xo, Wl[buf] + 16384 + w * 1024);
    };

    // ---- read addresses
    const int ar = mg * 16 + l15;              // A row (ar&15 == l15)
    const int wc0 = cg * 48 + l15;             // W cols for ct=0,1,2
    const int wc1 = wc0 + 16, wc2 = wc0 + 32;

    f32x4 acc[3];
#pragma unroll
    for (int j = 0; j < 3; ++j) acc[j] = (f32x4){0.f, 0.f, 0.f, 0.f};

    stage(0, 0);
    __syncthreads();

#pragma unroll
    for (int kt = 0; kt < 12; ++kt) {
        const int cur = kt & 1;
        if (kt < 11) stage(kt + 1, cur ^ 1);
        const char* Ab = xA[cur];
        const char* Wb = Wl[cur];
#pragma unroll
        for (int ks = 0; ks < 2; ++ks) {
            const int gf = ks * 8 + 2 * l4;
            float4 a0 = *(const float4*)(Ab + ar * 256 + (((gf    ) ^ l15) << 4));
            float4 a1 = *(const float4*)(Ab + ar * 256 + (((gf + 1) ^ l15) << 4));
            short8 af = pack_bf8(a0, a1);
            const int gw = ks * 4 + l4;
            short8 wf0 = *(const short8*)(Wb + wc0 * 128 + ((gw ^ (wc0 & 7)) << 4));
            short8 wf1 = *(const short8*)(Wb + wc1 * 128 + ((gw ^ (wc1 & 7)) << 4));
            short8 wf2 = *(const short8*)(Wb + wc2 * 128 + ((gw ^ (wc2 & 7)) << 4));
            acc[0] = __builtin_amdgcn_mfma_f32_16x16x32_bf16(af, wf0, acc[0], 0, 0, 0);
            acc[1] = __builtin_amdgcn_mfma_f32_16x16x32_bf16(af, wf1, acc[1], 0, 0, 0);
            acc[2] = __builtin_amdgcn_mfma_f32_16x16x32_bf16(af, wf2, acc[2], 0, 0, 0);
        }
        if (kt < 11) __syncthreads();
    }

    // ---- epilogue: Q (pre-scaled 1/8) / K direct; V via Vs transpose
    const int lrow = mg * 16 + l4 * 4;
    const size_t grow = (size_t)row0 + lrow;
#pragma unroll
    for (int ct = 0; ct < 3; ++ct) {
        const int cbase = cg * 48 + ct * 16;
        const int sel   = cbase >> 6;              // 0=Q 1=K 2=V (uniform per ct)
        const int cloc  = (cbase & 63) + l15;
#pragma unroll
        for (int r = 0; r < 4; ++r) {
            const float v = acc[ct][r];
            if (sel == 0)      Qg[(grow + r) * HS + cloc] = f2bf(v * 0.125f);
            else if (sel == 1) Kg[(grow + r) * HS + cloc] = f2bf(v);
            else               Vs[lrow + r][cloc] = v;
        }
    }
    __syncthreads();
    {   // Vt write: thread t -> col t>>3, rows (t&7)*4..+3
        const int vcol = t >> 3, vr0 = (t & 7) * 4;
        const int bb = row0 >> 12, s0 = row0 & 4095;
        union { short4_t s; uint_t u[2]; } vp;
        vp.u[0] = cvt_pk_bf16(Vs[vr0][vcol],     Vs[vr0 + 1][vcol]);
        vp.u[1] = cvt_pk_bf16(Vs[vr0 + 2][vcol], Vs[vr0 + 3][vcol]);
        *(short4_t*)(Vtg + ((size_t)bb * HS + vcol) * S_LEN + s0 + vr0) = vp.s;
    }
}

// ---------------- Flash attention: 64-q-row blocks, 6-way key parity ------------------
// 768 blocks (3/CU): (b, pair jp, parity v in 0..5). Block runs ranges jp and 63-jp;
// processes key-tiles tt ≡ v (mod 6). 4 waves = 4 q-subs share each staged K/V tile.
__global__ __launch_bounds__(256) void attn_kernel(
    const ushort_t* __restrict__ Qg, const ushort_t* __restrict__ Kg,
    const ushort_t* __restrict__ Vtg,
    ushort_t* __restrict__ pacc, float* __restrict__ pm, float* __restrict__ pl)
{
    __shared__ char smem[40960];   // K dbuf 16K | V dbuf 16K | P 4x2K
    const int t    = threadIdx.x;
    const int w    = t >> 6;
    const int lane = t & 63;
    const int l15  = lane & 15;
    const int l4   = lane >> 4;

    const int g  = blockIdx.x;
    const int b  = g & 3;                      // batch in low bits -> XCD spread
    const int rr = g >> 2;                     // 0..191
    const int jp = rr & 31;                    // pair index 0..31
    const int v  = rr >> 5;                    // key parity 0..5

    const ushort_t* Kb_ = Kg  + (size_t)b * S_LEN * HS;
    const ushort_t* Vb_ = Vtg + (size_t)b * HS * S_LEN;
    const ushort_t* Qb_ = Qg  + (size_t)b * S_LEN * HS;

    char* myP = smem + 32768 + w * 2048;       // P[16 q][64 k] bf16
    const int psw = (l15 & 7) << 4;

    auto stage = [&](int k0, int db) {
#pragma unroll
        for (int i = 0; i < 2; ++i) {
            const int row = w * 16 + i * 8 + (lane >> 3);
            const int c   = lane & 7;
            gl_lds16(Kb_ + (size_t)(k0 + row) * HS + ((c ^ (row & 7)) * 8),
                     smem + db * 8192 + w * 2048 + i * 1024);
            gl_lds16(Vb_ + (size_t)row * S_LEN + k0 + ((c ^ (row & 7)) * 8),
                     smem + 16384 + db * 8192 + w * 2048 + i * 1024);
        }
    };

    auto run_phase = [&](int r, int pidx) {
        const int q0r = r * BK;
        const int nt  = r + 1;
        const int q   = q0r + w * 16 + l15;
        const ushort_t* qrow = Qb_ + (size_t)q * HS;
        short8 qf0 = *(const short8*)(qrow + l4 * 8);
        short8 qf1 = *(const short8*)(qrow + 32 + l4 * 8);
        f32x4 acc[4];
#pragma unroll
        for (int j = 0; j < 4; ++j) acc[j] = (f32x4){0.f,0.f,0.f,0.f};
        float mm = -3e38f, ls = 0.f;

        __syncthreads();                       // prior-phase readers done
        if (v < nt) stage(v * BK, 0);
        int db = 0;
        for (int tt = v; tt < nt; tt += NPAR, db ^= 1) {
            __syncthreads();                   // staged(tt) complete (vmcnt drain)
            if (tt + NPAR < nt) stage((tt + NPAR) * BK, db ^ 1);
            const char* Kt  = smem + db * 8192;
            const char* Vt2 = smem + 16384 + db * 8192;

            f32x4 sT[4];
#pragma unroll
            for (int st = 0; st < 4; ++st) {
                const int krow = st * 16 + l15;
                const char* krb = Kt + krow * 128;
                const int sw = krow & 7;
                short8 kc0 = *(const short8*)(krb + ((l4 ^ sw) << 4));
                short8 kc1 = *(const short8*)(krb + (((4 + l4) ^ sw) << 4));
                f32x4 z = (f32x4){0.f,0.f,0.f,0.f};
                z = __builtin_amdgcn_mfma_f32_16x16x32_bf16(kc0, qf0, z, 0, 0, 0);
                z = __builtin_amdgcn_mfma_f32_16x16x32_bf16(kc1, qf1, z, 0, 0, 0);
                sT[st] = z;
            }
            if (tt == r) {                     // diagonal tile: causal mask
#pragma unroll
                for (int st = 0; st < 4; ++st)
#pragma unroll
                    for (int rr2 = 0; rr2 < 4; ++rr2)
                        if (tt * BK + st * 16 + l4 * 4 + rr2 > q) sT[st][rr2] = -3e38f;
            }
            float a0 = fmaxf(fmaxf(sT[0][0], sT[0][1]), fmaxf(sT[0][2], sT[0][3]));
            float a1 = fmaxf(fmaxf(sT[1][0], sT[1][1]), fmaxf(sT[1][2], sT[1][3]));
            float a2 = fmaxf(fmaxf(sT[2][0], sT[2][1]), fmaxf(sT[2][2], sT[2][3]));
            float a3 = fmaxf(fmaxf(sT[3][0], sT[3][1]), fmaxf(sT[3][2], sT[3][3]));
            float mt = fmaxf(fmaxf(a0, a1), fmaxf(a2, a3));
            if (__any(mt > mm + 8.f)) {        // rare: full max + rescale
                mt = fmaxf(mt, __shfl_xor(mt, 16));
                mt = fmaxf(mt, __shfl_xor(mt, 32));
                float mn = fmaxf(mm, mt);
                float corr = __expf(mm - mn);
                ls *= corr;
#pragma unroll
                for (int ds = 0; ds < 4; ++ds)
#pragma unroll
                    for (int rr2 = 0; rr2 < 4; ++rr2) acc[ds][rr2] *= corr;
                mm = mn;
            }
            char* pr = myP + l15 * 128;
            float la = 0.f;
#pragma unroll
            for (int st = 0; st < 4; ++st) {
                float p0 = __expf(sT[st][0] - mm);
                float p1 = __expf(sT[st][1] - mm);
                float p2 = __expf(sT[st][2] - mm);
                float p3 = __expf(sT[st][3] - mm);
                la += (p0 + p1) + (p2 + p3);
                uint2 pk; pk.x = cvt_pk_bf16(p0, p1); pk.y = cvt_pk_bf16(p2, p3);
                *(uint2*)(pr + ((st * 32 + l4 * 8) ^ psw)) = pk;
            }
            ls += la;
            short8 pb0 = *(const short8*)(pr + ((l4 * 16) ^ psw));
            short8 pb1 = *(const short8*)(pr + ((64 + l4 * 16) ^ psw));
#pragma unroll
            for (int ds = 0; ds < 4; ++ds) {
                const int vrow = ds * 16 + l15;
                const char* vrb = Vt2 + vrow * 128;
                const int sw2 = vrow & 7;
                short8 v0 = *(const short8*)(vrb + ((l4 ^ sw2) << 4));
                short8 v1 = *(const short8*)(vrb + (((4 + l4) ^ sw2) << 4));
                acc[ds] = __builtin_amdgcn_mfma_f32_16x16x32_bf16(v0, pb0, acc[ds], 0, 0, 0);
                acc[ds] = __builtin_amdgcn_mfma_f32_16x16x32_bf16(v1, pb1, acc[ds], 0, 0, 0);
            }
        }

        ls += __shfl_xor(ls, 16);
        ls += __shfl_xor(ls, 32);
        // bf16 partials (packed pairs)
        ushort_t* pa = pacc + ((size_t)pidx * 64 + w * 16 + l15) * 64 + l4 * 4;
#pragma unroll
        for (int ds = 0; ds < 4; ++ds) {
            uint2 pk;
            pk.x = cvt_pk_bf16(acc[ds][0], acc[ds][1]);
            pk.y = cvt_pk_bf16(acc[ds][2], acc[ds][3]);
            *(uint2*)(pa + ds * 16) = pk;
        }
        if (l4 == 0) {
            pm[pidx * 64 + w * 16 + l15] = mm;
            pl[pidx * 64 + w * 16 + l15] = ls;
        }
    };

    run_phase(jp,      (b * 64 + jp) * NPAR + v);
    run_phase(63 - jp, (b * 64 + 63 - jp) * NPAR + v);
}

// ---------------- Stage 2: combine the 6 parity partials per 64-row range -------------
__global__ __launch_bounds__(256) void combine_kernel(
    const ushort_t* __restrict__ pacc, const float* __restrict__ pm, const float* __restrict__ pl,
    float* __restrict__ out)
{
    const int g   = blockIdx.x;        // b*64 + r
    const int t   = threadIdx.x;
    const int row = t >> 2;            // 0..63
    const int d0  = (t & 3) * 16;
    float mv[NPAR], lv[NPAR];
#pragma unroll
    for (int p = 0; p < NPAR; ++p) {
        mv[p] = pm[(g * NPAR + p) * 64 + row];
        lv[p] = pl[(g * NPAR + p) * 64 + row];
    }
    float ms = mv[0];
#pragma unroll
    for (int p = 1; p < NPAR; ++p) ms = fmaxf(ms, mv[p]);
    float e[NPAR], ll = 0.f;
#pragma unroll
    for (int p = 0; p < NPAR; ++p) { e[p] = __expf(mv[p] - ms); ll += lv[p] * e[p]; }
    const float inv = 1.f / ll;
    float o[16];
#pragma unroll
    for (int i = 0; i < 16; ++i) o[i] = 0.f;
#pragma unroll
    for (int p = 0; p < NPAR; ++p) {
        const ushort_t* src = pacc + ((size_t)(g * NPAR + p) * 64 + row) * 64 + d0;
        short8 s0 = *(const short8*)(src);
        short8 s1 = *(const short8*)(src + 8);
#pragma unroll
        for (int i = 0; i < 8; ++i) {
            o[i]     += bf2f((ushort_t)s0[i]) * e[p];
            o[8 + i] += bf2f((ushort_t)s1[i]) * e[p];
        }
    }
    float4* op = (float4*)&out[((size_t)g * 64 + row) * 64 + d0];
#pragma unroll
    for (int i = 0; i < 4; ++i)
        op[i] = make_float4(o[i*4] * inv, o[i*4+1] * inv, o[i*4+2] * inv, o[i*4+3] * inv);
}

extern "C" void kernel_launch(void* const* d_in, const int* in_sizes, int n_in,
                              void* d_out, int out_size, void* d_ws, size_t ws_size,
                              hipStream_t stream) {
    const float* x  = (const float*)d_in[0];
    const float* Wq = (const float*)d_in[1];
    const float* Wk = (const float*)d_in[2];
    const float* Wv = (const float*)d_in[3];
    float* out = (float*)d_out;

    const int rows = in_sizes[0] / EMBD;   // B*S = 16384
    const int B    = rows / S_LEN;         // 4

    ushort_t* Qb = (ushort_t*)d_ws;
    ushort_t* Kb = Qb + (size_t)rows * HS;
    ushort_t* Vt = Kb + (size_t)rows * HS;
    ushort_t* Wt = Vt + (size_t)rows * HS;
    ushort_t* pacc = Wt + 192 * EMBD;                        // bf16 [B*64*6][64][64]
    float* pm = (float*)(pacc + (size_t)B * 64 * NPAR * 64 * 64);
    float* pl = pm + (size_t)B * 64 * NPAR * 64;

    hipLaunchKernelGGL(wprep_kernel, dim3(36), dim3(256), 0, stream, Wq, Wk, Wv, Wt);
    hipLaunchKernelGGL(qkv_kernel, dim3(rows / 32), dim3(512), 0, stream,
                       x, Wt, Qb, Kb, Vt);
    hipLaunchKernelGGL(attn_kernel, dim3(B * 32 * NPAR), dim3(256), 0, stream,
                       Qb, Kb, Vt, pacc, pm, pl);
    hipLaunchKernelGGL(combine_kernel, dim3(B * 64), dim3(256), 0, stream,
                       pacc, pm, pl, out);
}